// Round 1
// baseline (1797.676 us; speedup 1.0000x reference)
//
#include <hip/hip_runtime.h>
#include <math.h>

// IDMRFLoss on MI355X.
// Layer 0 (relu3_2): B=4, C=256, H=W=64  -> S=4096, weight 1.0
// Layer 1 (relu4_2): B=4, C=512, H=W=32  -> S=1024, weight 2.0 (style + content)
//
// Per (layer, batch):
//   1. normalize: mean_t over channels; gn = (gen-mean)/||.||, tn = (tar-mean)/||.||   [C,S] layout
//   2. sim[p,q] = sum_c tn[c,p]*gn[c,q]   (S x S fp32 GEMM, K=C), fused column-max of sim
//   3. colsum[q] = sum_p exp(2 - a_q*cd[p,q]),  a_q = 2/((1-colmax_q)/2 + eps)
//   4. kmax[p] = max_q exp(2 - a_q*cd[p,q]) / colsum[q];  acc = sum_p kmax
//   5. loss += w * -log(acc/S)
//
// Workspace layout (floats): sim 16.7M | gn 1.05M | tn 1.05M | colmax 4K | colsum 4K | kmax 4K | acc 16
// total ~76 MB, reused across the 8 (layer,batch) combos (stream-ordered).

#define MRF_EPS 1e-5f

__device__ __forceinline__ void atomicMaxFloat(float* addr, float v) {
    int* ai = (int*)addr;
    int old = __float_as_int(*(volatile float*)addr);
    while (__int_as_float(old) < v) {
        int assumed = old;
        old = atomicCAS(ai, assumed, __float_as_int(v));
        if (old == assumed) break;
    }
}

// ---- 1. channel-normalize gen & tar (per spatial position) ----
// block (64,4): tx = position within 64-tile (coalesced), ty = channel stripe
__global__ __launch_bounds__(256) void normalize_kernel(
    const float* __restrict__ gen, const float* __restrict__ tar,
    float* __restrict__ gn, float* __restrict__ tn, int C, int S) {
    int tx = threadIdx.x, ty = threadIdx.y;
    int s = blockIdx.x * 64 + tx;
    __shared__ float red[4][64], red2[4][64];
    __shared__ float smean[64], srg[64], srt[64];

    float sum = 0.f;
    for (int c = ty; c < C; c += 4) sum += tar[(size_t)c * S + s];
    red[ty][tx] = sum;
    __syncthreads();
    if (ty == 0) smean[tx] = (red[0][tx] + red[1][tx] + red[2][tx] + red[3][tx]) / (float)C;
    __syncthreads();
    float mean = smean[tx];

    float sg = 0.f, st = 0.f;
    for (int c = ty; c < C; c += 4) {
        float g = gen[(size_t)c * S + s] - mean;
        float t = tar[(size_t)c * S + s] - mean;
        sg += g * g;
        st += t * t;
    }
    red[ty][tx] = sg;
    red2[ty][tx] = st;
    __syncthreads();
    if (ty == 0) {
        srg[tx] = 1.f / sqrtf(red[0][tx] + red[1][tx] + red[2][tx] + red[3][tx]);
        srt[tx] = 1.f / sqrtf(red2[0][tx] + red2[1][tx] + red2[2][tx] + red2[3][tx]);
    }
    __syncthreads();
    float rg = srg[tx], rt = srt[tx];
    for (int c = ty; c < C; c += 4) {
        size_t idx = (size_t)c * S + s;
        gn[idx] = (gen[idx] - mean) * rg;
        tn[idx] = (tar[idx] - mean) * rt;
    }
}

__global__ void init_stats(float* __restrict__ colmax, float* __restrict__ colsum, int S) {
    int i = blockIdx.x * 256 + threadIdx.x;
    if (i < S) { colmax[i] = -INFINITY; colsum[i] = 0.f; }
}

// ---- 2. sim = tn^T * gn  (A,B both [K,S], K-major) + fused column max ----
// 128x128 tile, BK=8, 256 threads, 8x8 per thread (split 4+4 fragments: <=2-way LDS aliasing)
#define BM 128
#define BN 128
#define BK 8
__global__ __launch_bounds__(256) void gemm_colmax(
    const float* __restrict__ A, const float* __restrict__ B,
    float* __restrict__ C, float* __restrict__ colmax, int K, int S) {
    __shared__ float As[BK][BM];
    __shared__ float Bs[BK][BN + 4];
    __shared__ float redc[16][BN];

    int tid = threadIdx.x;
    int tx = tid & 15, ty = tid >> 4;
    int bp = blockIdx.y * BM, bq = blockIdx.x * BN;
    int lr = tid >> 5, lc = (tid & 31) * 4;

    float acc[8][8];
#pragma unroll
    for (int i = 0; i < 8; i++)
#pragma unroll
        for (int j = 0; j < 8; j++) acc[i][j] = 0.f;

    for (int k0 = 0; k0 < K; k0 += BK) {
        float4 a4 = *(const float4*)(A + (size_t)(k0 + lr) * S + bp + lc);
        float4 b4 = *(const float4*)(B + (size_t)(k0 + lr) * S + bq + lc);
        *(float4*)&As[lr][lc] = a4;
        *(float4*)&Bs[lr][lc] = b4;
        __syncthreads();
#pragma unroll
        for (int k = 0; k < BK; k++) {
            float a[8], b[8];
            *(float4*)&a[0] = *(const float4*)&As[k][ty * 4];
            *(float4*)&a[4] = *(const float4*)&As[k][64 + ty * 4];
            *(float4*)&b[0] = *(const float4*)&Bs[k][tx * 4];
            *(float4*)&b[4] = *(const float4*)&Bs[k][64 + tx * 4];
#pragma unroll
            for (int i = 0; i < 8; i++)
#pragma unroll
                for (int j = 0; j < 8; j++) acc[i][j] += a[i] * b[j];
        }
        __syncthreads();
    }

    // write C (coalesced: lanes tx consecutive -> 256B segments)
#pragma unroll
    for (int ih = 0; ih < 2; ih++)
#pragma unroll
        for (int i = 0; i < 4; i++) {
            int p = bp + ih * 64 + ty * 4 + i;
            int ai = ih * 4 + i;
            size_t off = (size_t)p * S + bq;
            *(float4*)(C + off + tx * 4)      = make_float4(acc[ai][0], acc[ai][1], acc[ai][2], acc[ai][3]);
            *(float4*)(C + off + 64 + tx * 4) = make_float4(acc[ai][4], acc[ai][5], acc[ai][6], acc[ai][7]);
        }

    // column max over this block's 128 p-rows
#pragma unroll
    for (int j = 0; j < 4; j++) {
        float m0 = acc[0][j], m1 = acc[0][j + 4];
#pragma unroll
        for (int i = 1; i < 8; i++) {
            m0 = fmaxf(m0, acc[i][j]);
            m1 = fmaxf(m1, acc[i][j + 4]);
        }
        redc[ty][tx * 4 + j] = m0;
        redc[ty][64 + tx * 4 + j] = m1;
    }
    __syncthreads();
    if (tid < BN) {
        float m = redc[0][tid];
#pragma unroll
        for (int r = 1; r < 16; r++) m = fmaxf(m, redc[r][tid]);
        atomicMaxFloat(colmax + bq + tid, m);
    }
}

// ---- 3. column sums of dist ----
// grid (S/64, 8); block (64,4); each block sums a p-chunk for 64 columns, atomicAdd once per q
__global__ __launch_bounds__(256) void colsum_kernel(
    const float* __restrict__ sim, const float* __restrict__ colmax,
    float* __restrict__ colsum, int S, int chunk) {
    int tx = threadIdx.x, ty = threadIdx.y;
    int q = blockIdx.x * 64 + tx;
    int p0 = blockIdx.y * chunk;
    float a = 2.f / ((1.f - colmax[q]) * 0.5f + MRF_EPS);
    float s = 0.f;
    for (int p = p0 + ty; p < p0 + chunk; p += 4) {
        float cd = (1.f - sim[(size_t)p * S + q]) * 0.5f;
        s += expf(2.f - a * cd);
    }
    __shared__ float red[4][64];
    red[ty][tx] = s;
    __syncthreads();
    if (ty == 0) atomicAdd(colsum + q, red[0][tx] + red[1][tx] + red[2][tx] + red[3][tx]);
}

// ---- 4. row max of cs ----
// one wave per row p (contiguous reads along q)
__global__ __launch_bounds__(256) void rowmax_kernel(
    const float* __restrict__ sim, const float* __restrict__ colmax,
    const float* __restrict__ colsum, float* __restrict__ kmax, int S) {
    int wave = threadIdx.x >> 6, lane = threadIdx.x & 63;
    int p = blockIdx.x * 4 + wave;
    const float* row = sim + (size_t)p * S;
    float m = -INFINITY;
    for (int q = lane; q < S; q += 64) {
        float a = 2.f / ((1.f - colmax[q]) * 0.5f + MRF_EPS);
        float cd = (1.f - row[q]) * 0.5f;
        float v = expf(2.f - a * cd) / colsum[q];
        m = fmaxf(m, v);
    }
#pragma unroll
    for (int off = 32; off >= 1; off >>= 1) m = fmaxf(m, __shfl_down(m, off, 64));
    if (lane == 0) kmax[p] = m;
}

// ---- 5. sum kmax -> acc slot ----
__global__ void reduce_sum(const float* __restrict__ v, int n, float* __restrict__ out) {
    __shared__ float red[256];
    int tid = threadIdx.x;
    float s = 0.f;
    for (int i = tid; i < n; i += 256) s += v[i];
    red[tid] = s;
    __syncthreads();
    for (int h = 128; h > 0; h >>= 1) {
        if (tid < h) red[tid] += red[tid + h];
        __syncthreads();
    }
    if (tid == 0) out[0] = red[0];
}

__global__ void finalize_kernel(const float* __restrict__ acc, float* __restrict__ out) {
    float loss = 0.f;
    for (int b = 0; b < 4; b++) loss += -logf(acc[b] * (1.f / 4096.f));
    for (int b = 0; b < 4; b++) loss += -2.f * logf(acc[4 + b] * (1.f / 1024.f));
    out[0] = loss;
}

extern "C" void kernel_launch(void* const* d_in, const int* in_sizes, int n_in,
                              void* d_out, int out_size, void* d_ws, size_t ws_size,
                              hipStream_t stream) {
    const float* gen3 = (const float*)d_in[0];
    const float* tar3 = (const float*)d_in[1];
    const float* gen4 = (const float*)d_in[2];
    const float* tar4 = (const float*)d_in[3];

    float* ws = (float*)d_ws;
    float* sim = ws;                       // 4096*4096
    float* gn = ws + 16777216;             // 1048576 (max C*S)
    float* tn = gn + 1048576;              // 1048576
    float* colmax = tn + 1048576;          // 4096
    float* colsum = colmax + 4096;         // 4096
    float* kmax = colsum + 4096;           // 4096
    float* acc = kmax + 4096;              // 16
    // total ~18.9M floats ~ 76 MB

    for (int layer = 0; layer < 2; layer++) {
        const int C = (layer == 0) ? 256 : 512;
        const int S = (layer == 0) ? 4096 : 1024;
        const float* gen = (layer == 0) ? gen3 : gen4;
        const float* tar = (layer == 0) ? tar3 : tar4;
        for (int b = 0; b < 4; b++) {
            const float* g = gen + (size_t)b * C * S;
            const float* t = tar + (size_t)b * C * S;
            normalize_kernel<<<S / 64, dim3(64, 4), 0, stream>>>(g, t, gn, tn, C, S);
            init_stats<<<(S + 255) / 256, 256, 0, stream>>>(colmax, colsum, S);
            gemm_colmax<<<dim3(S / BN, S / BM), 256, 0, stream>>>(tn, gn, sim, colmax, C, S);
            colsum_kernel<<<dim3(S / 64, 8), dim3(64, 4), 0, stream>>>(sim, colmax, colsum, S, S / 8);
            rowmax_kernel<<<S / 4, 256, 0, stream>>>(sim, colmax, colsum, kmax, S);
            reduce_sum<<<1, 256, 0, stream>>>(kmax, S, acc + layer * 4 + b);
        }
    }
    finalize_kernel<<<1, 1, 0, stream>>>(acc, (float*)d_out);
}

// Round 2
// 880.580 us; speedup vs baseline: 2.0415x; 2.0415x over previous
//
#include <hip/hip_runtime.h>
#include <math.h>

// IDMRFLoss on MI355X — R1: bf16 MFMA GEMM + single-pass normalize/transpose.
// Layer 0 (relu3_2): B=4, C=256, S=4096, weight 1.0
// Layer 1 (relu4_2): B=4, C=512, S=1024, weight 2.0 (style + content)
//
// Pipeline per layer:
//   stats:  per position s: mean(tar_c), 1/||gen-mean||, 1/||tar-mean||  (single pass, sum/sumsq identities)
//   apply:  LDS-transpose [C,S]fp32 -> [S,C]bf16 normalized gnT/tnT (all batches)
//   per batch: init colmax/colsum; MFMA gemm sim=tnT·gnT^T (fp32 out) + fused colmax;
//              colsum pass; rowmax pass (fused partial-sum atomicAdd into acc[combo])
//   finalize: loss = sum_b -log(acc/S) [+2x for layer4]

#define MRF_EPS 1e-5f

typedef __attribute__((ext_vector_type(8))) short bf16x8;
typedef __attribute__((ext_vector_type(4))) float f32x4;
typedef unsigned short ushort_t;

__device__ __forceinline__ void atomicMaxFloat(float* addr, float v) {
    int* ai = (int*)addr;
    int old = __float_as_int(*(volatile float*)addr);
    while (__int_as_float(old) < v) {
        int assumed = old;
        old = atomicCAS(ai, assumed, __float_as_int(v));
        if (old == assumed) break;
    }
}

__device__ __forceinline__ ushort_t f2bf(float x) {
    unsigned u = __float_as_uint(x);
    u += 0x7FFFu + ((u >> 16) & 1u);   // round-to-nearest-even
    return (ushort_t)(u >> 16);
}

// ---- stats: one pass, per position: mean(tar), rsq norms ----
// grid (S/64, B), block (64,4)
__global__ __launch_bounds__(256) void stats_kernel(
    const float* __restrict__ gen, const float* __restrict__ tar,
    float* __restrict__ mean, float* __restrict__ rg, float* __restrict__ rt,
    int C, int S) {
    int tx = threadIdx.x, ty = threadIdx.y;
    int b = blockIdx.y;
    int s = blockIdx.x * 64 + tx;
    const float* g = gen + (size_t)b * C * S;
    const float* t = tar + (size_t)b * C * S;

    float st = 0.f, st2 = 0.f, sg = 0.f, sg2 = 0.f;
    for (int c = ty; c < C; c += 4) {
        float tv = t[(size_t)c * S + s];
        float gv = g[(size_t)c * S + s];
        st += tv; st2 += tv * tv; sg += gv; sg2 += gv * gv;
    }
    __shared__ float4 red[4][64];
    red[ty][tx] = make_float4(st, st2, sg, sg2);
    __syncthreads();
    if (ty == 0) {
        float4 a = red[0][tx], b4 = red[1][tx], c4 = red[2][tx], d4 = red[3][tx];
        float sts = a.x + b4.x + c4.x + d4.x;
        float st2s = a.y + b4.y + c4.y + d4.y;
        float sgs = a.z + b4.z + c4.z + d4.z;
        float sg2s = a.w + b4.w + c4.w + d4.w;
        float m = sts / (float)C;
        float nt2 = st2s - m * sts;                       // ||t-m||^2
        float ng2 = sg2s - 2.f * m * sgs + m * sts;       // ||g-m||^2 (C*m^2 = m*sts)
        int idx = b * S + s;
        mean[idx] = m;
        rt[idx] = rsqrtf(nt2);
        rg[idx] = rsqrtf(ng2);
    }
}

// ---- apply: normalized transpose to bf16 [S,C] ----
// grid (S/64, C/64, B), block (64,4)
__global__ __launch_bounds__(256) void apply_kernel(
    const float* __restrict__ gen, const float* __restrict__ tar,
    const float* __restrict__ mean, const float* __restrict__ rg, const float* __restrict__ rt,
    ushort_t* __restrict__ gnT, ushort_t* __restrict__ tnT, int C, int S) {
    int tx = threadIdx.x, ty = threadIdx.y;
    int b = blockIdx.z;
    int s0 = blockIdx.x * 64, c0 = blockIdx.y * 64;
    const float* g = gen + (size_t)b * C * S;
    const float* t = tar + (size_t)b * C * S;

    __shared__ float tg[64][65], tt[64][65];
#pragma unroll
    for (int i = 0; i < 16; i++) {
        int cl = i * 4 + ty;
        tg[cl][tx] = g[(size_t)(c0 + cl) * S + s0 + tx];
        tt[cl][tx] = t[(size_t)(c0 + cl) * S + s0 + tx];
    }
    __syncthreads();
#pragma unroll
    for (int i = 0; i < 16; i++) {
        int sl = i * 4 + ty;
        int idx = b * S + s0 + sl;
        float m = mean[idx], rgv = rg[idx], rtv = rt[idx];
        size_t off = ((size_t)b * S + s0 + sl) * C + c0 + tx;
        gnT[off] = f2bf((tg[tx][sl] - m) * rgv);
        tnT[off] = f2bf((tt[tx][sl] - m) * rtv);
    }
}

__global__ void init_stats(float* __restrict__ colmax, float* __restrict__ colsum, int S) {
    int i = blockIdx.x * 256 + threadIdx.x;
    if (i < S) { colmax[i] = -INFINITY; colsum[i] = 0.f; }
}

__global__ void zero_acc(float* __restrict__ acc) {
    if (threadIdx.x < 8) acc[threadIdx.x] = 0.f;
}

// ---- MFMA GEMM: sim[p,q] = sum_k tnT[p,k]*gnT[q,k], fused column(q) max ----
// 128x128 tile, BK=32, 4 waves each 64x64 (4x4 tiles of 16x16x32 MFMA)
// LDS tiles [128][40] bf16 (row-major, +8 pad): frag read = ds_read_b128, 2-way bank (free)
__global__ __launch_bounds__(256) void gemm_mfma(
    const ushort_t* __restrict__ A,   // tnT [S][C]
    const ushort_t* __restrict__ B,   // gnT [S][C]
    float* __restrict__ sim, float* __restrict__ colmax, int K, int S) {
    __shared__ __align__(16) ushort_t As[128 * 40];
    __shared__ __align__(16) ushort_t Bs[128 * 40];

    int tid = threadIdx.x;
    int lane = tid & 63, wave = tid >> 6;
    int wm = (wave & 1) * 64, wn = (wave >> 1) * 64;
    int lm = lane & 15, quad = lane >> 4;
    int p0 = blockIdx.y * 128, q0 = blockIdx.x * 128;

    f32x4 acc[4][4];
#pragma unroll
    for (int t = 0; t < 4; t++)
#pragma unroll
        for (int u = 0; u < 4; u++) acc[t][u] = (f32x4){0.f, 0.f, 0.f, 0.f};

    int row0 = tid >> 1;               // chunk i = tid: row tid>>2? see below
    (void)row0;
    for (int k0 = 0; k0 < K; k0 += 32) {
        // stage: 128 rows x 32 bf16 = 512 chunks of 8 bf16 (16B); 2 chunks/thread/tile
#pragma unroll
        for (int part = 0; part < 2; part++) {
            int c = tid + part * 256;
            int row = c >> 2, seg = c & 3;
            *(float4*)&As[row * 40 + seg * 8] =
                *(const float4*)(A + (size_t)(p0 + row) * K + k0 + seg * 8);
            *(float4*)&Bs[row * 40 + seg * 8] =
                *(const float4*)(B + (size_t)(q0 + row) * K + k0 + seg * 8);
        }
        __syncthreads();
        bf16x8 af[4], bf[4];
#pragma unroll
        for (int t = 0; t < 4; t++)
            af[t] = *(const bf16x8*)&As[(wm + t * 16 + lm) * 40 + quad * 8];
#pragma unroll
        for (int u = 0; u < 4; u++)
            bf[u] = *(const bf16x8*)&Bs[(wn + u * 16 + lm) * 40 + quad * 8];
#pragma unroll
        for (int t = 0; t < 4; t++)
#pragma unroll
            for (int u = 0; u < 4; u++)
                acc[t][u] = __builtin_amdgcn_mfma_f32_16x16x32_bf16(af[t], bf[u], acc[t][u], 0, 0, 0);
        __syncthreads();
    }

    // epilogue: sim store (C/D layout: col=lane&15, row=quad*4+reg) + colmax
#pragma unroll
    for (int t = 0; t < 4; t++) {
        int pb = p0 + wm + t * 16 + quad * 4;
#pragma unroll
        for (int u = 0; u < 4; u++) {
            int q = q0 + wn + u * 16 + lm;
            f32x4 v = acc[t][u];
#pragma unroll
            for (int r = 0; r < 4; r++) sim[(size_t)(pb + r) * S + q] = v[r];
        }
    }
#pragma unroll
    for (int u = 0; u < 4; u++) {
        float m = -INFINITY;
#pragma unroll
        for (int t = 0; t < 4; t++) {
            f32x4 v = acc[t][u];
            m = fmaxf(m, fmaxf(fmaxf(v.x, v.y), fmaxf(v.z, v.w)));
        }
        m = fmaxf(m, __shfl_xor(m, 16, 64));
        m = fmaxf(m, __shfl_xor(m, 32, 64));
        if (lane < 16) atomicMaxFloat(colmax + q0 + wn + u * 16 + lane, m);
    }
}

// ---- column sums of dist ----
__global__ __launch_bounds__(256) void colsum_kernel(
    const float* __restrict__ sim, const float* __restrict__ colmax,
    float* __restrict__ colsum, int S, int chunk) {
    int tx = threadIdx.x, ty = threadIdx.y;
    int q = blockIdx.x * 64 + tx;
    int p0 = blockIdx.y * chunk;
    float a = 2.f / ((1.f - colmax[q]) * 0.5f + MRF_EPS);
    float s = 0.f;
    for (int p = p0 + ty; p < p0 + chunk; p += 4) {
        float cd = (1.f - sim[(size_t)p * S + q]) * 0.5f;
        s += expf(2.f - a * cd);
    }
    __shared__ float red[4][64];
    red[ty][tx] = s;
    __syncthreads();
    if (ty == 0) atomicAdd(colsum + q, red[0][tx] + red[1][tx] + red[2][tx] + red[3][tx]);
}

// ---- row max of cs, fused partial sum into acc[combo] ----
__global__ __launch_bounds__(256) void rowmax_kernel(
    const float* __restrict__ sim, const float* __restrict__ colmax,
    const float* __restrict__ colsum, float* __restrict__ acc, int S) {
    int wave = threadIdx.x >> 6, lane = threadIdx.x & 63;
    int p = blockIdx.x * 4 + wave;
    const float* row = sim + (size_t)p * S;
    float m = -INFINITY;
    for (int q = lane; q < S; q += 64) {
        float a = 2.f / ((1.f - colmax[q]) * 0.5f + MRF_EPS);
        float cd = (1.f - row[q]) * 0.5f;
        m = fmaxf(m, expf(2.f - a * cd) / colsum[q]);
    }
#pragma unroll
    for (int off = 32; off >= 1; off >>= 1) m = fmaxf(m, __shfl_down(m, off, 64));
    __shared__ float red[4];
    if (lane == 0) red[wave] = m;
    __syncthreads();
    if (threadIdx.x == 0) atomicAdd(acc, red[0] + red[1] + red[2] + red[3]);
}

__global__ void finalize_kernel(const float* __restrict__ acc, float* __restrict__ out) {
    float loss = 0.f;
    for (int b = 0; b < 4; b++) loss += -logf(acc[b] * (1.f / 4096.f));
    for (int b = 0; b < 4; b++) loss += -2.f * logf(acc[4 + b] * (1.f / 1024.f));
    out[0] = loss;
}

extern "C" void kernel_launch(void* const* d_in, const int* in_sizes, int n_in,
                              void* d_out, int out_size, void* d_ws, size_t ws_size,
                              hipStream_t stream) {
    const float* gen3 = (const float*)d_in[0];
    const float* tar3 = (const float*)d_in[1];
    const float* gen4 = (const float*)d_in[2];
    const float* tar4 = (const float*)d_in[3];

    float* ws = (float*)d_ws;
    float* sim = ws;                         // 16.78M floats
    float* mean = ws + 16777216;             // 16384
    float* rg = mean + 16384;                // 16384
    float* rt = rg + 16384;                  // 16384
    float* colmax = rt + 16384;              // 4096
    float* colsum = colmax + 4096;           // 4096
    float* acc = colsum + 4096;              // 8
    ushort_t* gnT = (ushort_t*)(acc + 64);   // 4*4096*256 bf16 = 4.19M ushort
    ushort_t* tnT = gnT + 4 * 4096 * 256;    // same
    // total ~ 16.85M floats + 8.4M ushort ~ 84 MB

    zero_acc<<<1, 64, 0, stream>>>(acc);

    for (int layer = 0; layer < 2; layer++) {
        const int C = (layer == 0) ? 256 : 512;
        const int S = (layer == 0) ? 4096 : 1024;
        const float* gen = (layer == 0) ? gen3 : gen4;
        const float* tar = (layer == 0) ? tar3 : tar4;

        stats_kernel<<<dim3(S / 64, 4), dim3(64, 4), 0, stream>>>(gen, tar, mean, rg, rt, C, S);
        apply_kernel<<<dim3(S / 64, C / 64, 4), dim3(64, 4), 0, stream>>>(
            gen, tar, mean, rg, rt, gnT, tnT, C, S);

        for (int b = 0; b < 4; b++) {
            const ushort_t* a = tnT + (size_t)b * S * C;
            const ushort_t* bb = gnT + (size_t)b * S * C;
            init_stats<<<(S + 255) / 256, 256, 0, stream>>>(colmax, colsum, S);
            gemm_mfma<<<dim3(S / 128, S / 128), 256, 0, stream>>>(a, bb, sim, colmax, C, S);
            colsum_kernel<<<dim3(S / 64, 8), dim3(64, 4), 0, stream>>>(sim, colmax, colsum, S, S / 8);
            rowmax_kernel<<<S / 4, 256, 0, stream>>>(sim, colmax, colsum, acc + layer * 4 + b, S);
        }
    }
    finalize_kernel<<<1, 1, 0, stream>>>(acc, (float*)d_out);
}

// Round 3
// 515.436 us; speedup vs baseline: 3.4877x; 1.7084x over previous
//
#include <hip/hip_runtime.h>
#include <math.h>

// IDMRFLoss on MI355X — R2: blocked sim layout + coalesced f32x4 everywhere,
// XOR-swizzled LDS in the MFMA gemm, ILP'd stats kernel.
//
// Layer 0 (relu3_2): B=4, C=256, S=4096, weight 1.0
// Layer 1 (relu4_2): B=4, C=512, S=1024, weight 2.0 (style + content)
//
// sim blocked layout (per 128x128 block at (by,bx)):
//   base = (by*(S/128)+bx)*16384 + waveSlot*4096 + (t*4+u)*256 + quad*64 + lm*4 + r
//   element (p,q): p = by*128 + (waveSlot&1)*64 + t*16 + quad*4 + r
//                  q = bx*128 + (waveSlot>>1)*64 + u*16 + lm

#define MRF_EPS 1e-5f

typedef __attribute__((ext_vector_type(8))) short bf16x8;
typedef __attribute__((ext_vector_type(4))) float f32x4;
typedef unsigned short ushort_t;
struct __align__(8) ushort4_t { ushort_t x, y, z, w; };

__device__ __forceinline__ void atomicMaxFloat(float* addr, float v) {
    int* ai = (int*)addr;
    int old = __float_as_int(*(volatile float*)addr);
    while (__int_as_float(old) < v) {
        int assumed = old;
        old = atomicCAS(ai, assumed, __float_as_int(v));
        if (old == assumed) break;
    }
}

__device__ __forceinline__ ushort_t f2bf(float x) {
    unsigned u = __float_as_uint(x);
    u += 0x7FFFu + ((u >> 16) & 1u);
    return (ushort_t)(u >> 16);
}

// ---- stats: per position mean(tar), 1/||g-m||, 1/||t-m|| (single pass, f32x4 ILP) ----
// grid (S/64, B), block 256 = 16 position-quads x 16 channel stripes
__global__ __launch_bounds__(256) void stats_kernel(
    const float* __restrict__ gen, const float* __restrict__ tar,
    float* __restrict__ mean, float* __restrict__ rg, float* __restrict__ rt,
    int C, int S) {
    int tid = threadIdx.x;
    int tx = tid & 15, ty = tid >> 4;
    int b = blockIdx.y;
    int s0 = blockIdx.x * 64;
    const float* g = gen + (size_t)b * C * S + s0 + tx * 4;
    const float* t = tar + (size_t)b * C * S + s0 + tx * 4;

    f32x4 st = {0.f, 0.f, 0.f, 0.f}, st2 = st, sg = st, sg2 = st;
    for (int c = ty; c < C; c += 16) {
        f32x4 tv = *(const f32x4*)(t + (size_t)c * S);
        f32x4 gv = *(const f32x4*)(g + (size_t)c * S);
        st += tv; st2 += tv * tv; sg += gv; sg2 += gv * gv;
    }
    __shared__ f32x4 red[4][16][16];
    __shared__ f32x4 red2[4][16];
    red[0][ty][tx] = st; red[1][ty][tx] = st2; red[2][ty][tx] = sg; red[3][ty][tx] = sg2;
    __syncthreads();
    if (tid < 64) {
        int stat = tid >> 4, x = tid & 15;
        f32x4 s = red[stat][0][x];
#pragma unroll
        for (int j = 1; j < 16; j++) s += red[stat][j][x];
        red2[stat][x] = s;
    }
    __syncthreads();
    if (tid < 16) {
        f32x4 sts = red2[0][tid], st2s = red2[1][tid], sgs = red2[2][tid], sg2s = red2[3][tid];
        f32x4 m, vrt, vrg;
        float invC = 1.f / (float)C;
#pragma unroll
        for (int e = 0; e < 4; e++) {
            float mm = sts[e] * invC;
            m[e] = mm;
            vrt[e] = rsqrtf(st2s[e] - mm * sts[e]);
            vrg[e] = rsqrtf(sg2s[e] - 2.f * mm * sgs[e] + mm * sts[e]);
        }
        int idx = b * S + s0 + tid * 4;
        *(f32x4*)(mean + idx) = m;
        *(f32x4*)(rt + idx) = vrt;
        *(f32x4*)(rg + idx) = vrg;
    }
}

// ---- apply: normalized transpose [C,S]fp32 -> [S,C]bf16, ushort4 writes ----
// grid (S/64, C/64, B), block 256
__global__ __launch_bounds__(256) void apply_kernel(
    const float* __restrict__ gen, const float* __restrict__ tar,
    const float* __restrict__ mean, const float* __restrict__ rg, const float* __restrict__ rt,
    ushort_t* __restrict__ gnT, ushort_t* __restrict__ tnT, int C, int S) {
    int tid = threadIdx.x;
    int b = blockIdx.z;
    int s0 = blockIdx.x * 64, c0 = blockIdx.y * 64;
    const float* g = gen + (size_t)b * C * S;
    const float* t = tar + (size_t)b * C * S;

    __shared__ float tg[64][65], tt[64][65];
    int tx = tid & 63, tw = tid >> 6;
#pragma unroll
    for (int i = 0; i < 16; i++) {
        int cl = tw * 16 + i;
        tg[cl][tx] = g[(size_t)(c0 + cl) * S + s0 + tx];
        tt[cl][tx] = t[(size_t)(c0 + cl) * S + s0 + tx];
    }
    __syncthreads();
    int cq = tid & 15;
#pragma unroll
    for (int j = 0; j < 4; j++) {
        int sl = (tid >> 4) * 4 + j;
        int idx = b * S + s0 + sl;
        float m = mean[idx], rgv = rg[idx], rtv = rt[idx];
        ushort4_t og, ot;
        og.x = f2bf((tg[cq * 4 + 0][sl] - m) * rgv);
        og.y = f2bf((tg[cq * 4 + 1][sl] - m) * rgv);
        og.z = f2bf((tg[cq * 4 + 2][sl] - m) * rgv);
        og.w = f2bf((tg[cq * 4 + 3][sl] - m) * rgv);
        ot.x = f2bf((tt[cq * 4 + 0][sl] - m) * rtv);
        ot.y = f2bf((tt[cq * 4 + 1][sl] - m) * rtv);
        ot.z = f2bf((tt[cq * 4 + 2][sl] - m) * rtv);
        ot.w = f2bf((tt[cq * 4 + 3][sl] - m) * rtv);
        size_t off = (size_t)idx * C + c0 + cq * 4;
        *(ushort4_t*)(gnT + off) = og;
        *(ushort4_t*)(tnT + off) = ot;
    }
}

__global__ void init_stats(float* __restrict__ colmax, float* __restrict__ colsum, int n) {
    int i = blockIdx.x * 256 + threadIdx.x;
    if (i < n) { colmax[i] = -INFINITY; colsum[i] = 0.f; }
}

__global__ void zero_acc(float* __restrict__ acc) {
    if (threadIdx.x < 8) acc[threadIdx.x] = 0.f;
}

// ---- MFMA GEMM: sim[p,q] = sum_k A[p,k]*B[q,k] (blocked-layout store) + colmax ----
// 128x128 tile, BK=32, 4 waves x (64x64). XOR-swizzled LDS, row stride 32 elems.
__global__ __launch_bounds__(256) void gemm_mfma(
    const ushort_t* __restrict__ A, const ushort_t* __restrict__ B,
    float* __restrict__ sim, float* __restrict__ colmax,
    int K, int S, size_t abStride, size_t simStride, int cmStride) {
    int z = blockIdx.z;
    A += z * abStride; B += z * abStride;
    sim += z * simStride; colmax += z * cmStride;

    __shared__ __align__(16) ushort_t As[128 * 32];
    __shared__ __align__(16) ushort_t Bs[128 * 32];

    int tid = threadIdx.x;
    int lane = tid & 63, wave = tid >> 6;
    int wm = (wave & 1) * 64, wn = (wave >> 1) * 64;
    int lm = lane & 15, quad = lane >> 4;
    int p0 = blockIdx.y * 128, q0 = blockIdx.x * 128;

    f32x4 acc[4][4];
#pragma unroll
    for (int t = 0; t < 4; t++)
#pragma unroll
        for (int u = 0; u < 4; u++) acc[t][u] = (f32x4){0.f, 0.f, 0.f, 0.f};

    int swr = (lm >> 1) & 3;
    for (int k0 = 0; k0 < K; k0 += 32) {
#pragma unroll
        for (int part = 0; part < 2; part++) {
            int c = tid + part * 256;
            int row = c >> 2, seg = c & 3;
            int sw = seg ^ ((row >> 1) & 3);
            *(float4*)&As[row * 32 + sw * 8] =
                *(const float4*)(A + (size_t)(p0 + row) * K + k0 + seg * 8);
            *(float4*)&Bs[row * 32 + sw * 8] =
                *(const float4*)(B + (size_t)(q0 + row) * K + k0 + seg * 8);
        }
        __syncthreads();
        bf16x8 af[4], bfr[4];
#pragma unroll
        for (int t = 0; t < 4; t++)
            af[t] = *(const bf16x8*)&As[(wm + t * 16 + lm) * 32 + (quad ^ swr) * 8];
#pragma unroll
        for (int u = 0; u < 4; u++)
            bfr[u] = *(const bf16x8*)&Bs[(wn + u * 16 + lm) * 32 + (quad ^ swr) * 8];
#pragma unroll
        for (int t = 0; t < 4; t++)
#pragma unroll
            for (int u = 0; u < 4; u++)
                acc[t][u] = __builtin_amdgcn_mfma_f32_16x16x32_bf16(af[t], bfr[u], acc[t][u], 0, 0, 0);
        __syncthreads();
    }

    // blocked-layout store: per (t,u) each wave writes 4KB contiguous
    size_t base = ((size_t)(blockIdx.y * (S >> 7) + blockIdx.x)) * 16384
                + (size_t)(wave * 4096 + lane * 4);
#pragma unroll
    for (int t = 0; t < 4; t++)
#pragma unroll
        for (int u = 0; u < 4; u++)
            *(f32x4*)(sim + base + (t * 4 + u) * 256) = acc[t][u];

    // column max (q = q0 + wn + u*16 + lm)
#pragma unroll
    for (int u = 0; u < 4; u++) {
        float m = -INFINITY;
#pragma unroll
        for (int t = 0; t < 4; t++) {
            f32x4 v = acc[t][u];
            m = fmaxf(m, fmaxf(fmaxf(v.x, v.y), fmaxf(v.z, v.w)));
        }
        m = fmaxf(m, __shfl_xor(m, 16, 64));
        m = fmaxf(m, __shfl_xor(m, 32, 64));
        if (lane < 16) atomicMaxFloat(colmax + q0 + wn + u * 16 + lane, m);
    }
}

// ---- column sums of dist (blocked reads, f32x4) ----
// grid (nQB, nPB, NB), block 256: thread -> (cg,sub,u,lm); covers 64 p per thread
__global__ __launch_bounds__(256) void colsum_kernel(
    const float* __restrict__ sim, const float* __restrict__ colmax,
    float* __restrict__ colsum, int S, size_t simStride, int cmStride) {
    int z = blockIdx.z;
    sim += (size_t)z * simStride; colmax += z * cmStride; colsum += z * cmStride;
    int tid = threadIdx.x, lane = tid & 63;
    int u = lane >> 4, lm = lane & 15;
    int sub = (tid >> 6) & 1, cg = tid >> 7;
    int bx = blockIdx.x, by = blockIdx.y;
    int nQB = S >> 7;
    int q = bx * 128 + cg * 64 + u * 16 + lm;
    float c1 = 1.f / ((1.f - colmax[q]) * 0.5f + MRF_EPS);
    float c0 = 2.f - c1;
    const float* base = sim + ((size_t)(by * nQB + bx)) * 16384
                      + (size_t)((sub | (cg << 1)) * 4096 + u * 256 + lm * 4);
    float s = 0.f;
#pragma unroll
    for (int t = 0; t < 4; t++)
#pragma unroll
        for (int quad = 0; quad < 4; quad++) {
            f32x4 v = *(const f32x4*)(base + t * 1024 + quad * 64);
            s += __expf(c0 + c1 * v[0]) + __expf(c0 + c1 * v[1])
               + __expf(c0 + c1 * v[2]) + __expf(c0 + c1 * v[3]);
        }
    atomicAdd(colsum + q, s);
}

// ---- row max of cs, fused partial sum (blocked reads, f32x4 = 4 rows/lane) ----
// grid (S/16, NB), block 256: wave -> row group (by,sub,t,quad), lanes scan columns
__global__ __launch_bounds__(256) void rowmax_kernel(
    const float* __restrict__ sim, const float* __restrict__ colmax,
    const float* __restrict__ colsum, float* __restrict__ acc, int S,
    size_t simStride, int cmStride) {
    int z = blockIdx.y;
    sim += (size_t)z * simStride; colmax += z * cmStride; colsum += z * cmStride;
    int wave = threadIdx.x >> 6, lane = threadIdx.x & 63;
    int g = blockIdx.x * 4 + wave;
    int by = g >> 5, rem = g & 31;
    int sub = rem >> 4, t = (rem >> 2) & 3, quad = rem & 3;
    int u = lane >> 4, lm = lane & 15;
    int nQB = S >> 7;
    f32x4 m = {-INFINITY, -INFINITY, -INFINITY, -INFINITY};
    for (int bx = 0; bx < nQB; bx++) {
#pragma unroll
        for (int cg = 0; cg < 2; cg++) {
            int q = bx * 128 + cg * 64 + u * 16 + lm;
            float c1 = 1.f / ((1.f - colmax[q]) * 0.5f + MRF_EPS);
            float c0 = 2.f - c1;
            float rcs = 1.f / colsum[q];
            const float* ptr = sim + ((size_t)(by * nQB + bx)) * 16384
                             + (size_t)((sub | (cg << 1)) * 4096 + (t * 4 + u) * 256 + quad * 64 + lm * 4);
            f32x4 v = *(const f32x4*)ptr;
#pragma unroll
            for (int r = 0; r < 4; r++)
                m[r] = fmaxf(m[r], __expf(c0 + c1 * v[r]) * rcs);
        }
    }
#pragma unroll
    for (int off = 32; off >= 1; off >>= 1)
#pragma unroll
        for (int e = 0; e < 4; e++)
            m[e] = fmaxf(m[e], __shfl_xor(m[e], off, 64));
    __shared__ float partial[4];
    if (lane == 0) partial[wave] = m[0] + m[1] + m[2] + m[3];
    __syncthreads();
    if (threadIdx.x == 0)
        atomicAdd(acc + z, partial[0] + partial[1] + partial[2] + partial[3]);
}

__global__ void finalize_kernel(const float* __restrict__ acc, float* __restrict__ out) {
    float loss = 0.f;
    for (int b = 0; b < 4; b++) loss += -logf(acc[b] * (1.f / 4096.f));
    for (int b = 0; b < 4; b++) loss += -2.f * logf(acc[4 + b] * (1.f / 1024.f));
    out[0] = loss;
}

extern "C" void kernel_launch(void* const* d_in, const int* in_sizes, int n_in,
                              void* d_out, int out_size, void* d_ws, size_t ws_size,
                              hipStream_t stream) {
    const float* gen3 = (const float*)d_in[0];
    const float* tar3 = (const float*)d_in[1];
    const float* gen4 = (const float*)d_in[2];
    const float* tar4 = (const float*)d_in[3];

    float* ws = (float*)d_ws;
    float* sim = ws;                         // 16.78M floats (layer4: 4 batches x 1M)
    float* mean = ws + 16777216;             // 16384
    float* rg = mean + 16384;                // 16384
    float* rt = rg + 16384;                  // 16384
    float* colmax = rt + 16384;              // 16384 (4 slots)
    float* colsum = colmax + 16384;          // 16384
    float* acc = colsum + 16384;             // 8 (+pad)
    ushort_t* gnT = (ushort_t*)(acc + 64);   // 4*4096*256 bf16
    ushort_t* tnT = gnT + 4 * 4096 * 256;

    zero_acc<<<1, 64, 0, stream>>>(acc);

    // ---- layer 0: C=256, S=4096, per-batch sim ----
    {
        const int C = 256, S = 4096;
        stats_kernel<<<dim3(S / 64, 4), 256, 0, stream>>>(gen3, tar3, mean, rg, rt, C, S);
        apply_kernel<<<dim3(S / 64, C / 64, 4), 256, 0, stream>>>(
            gen3, tar3, mean, rg, rt, gnT, tnT, C, S);
        for (int b = 0; b < 4; b++) {
            const ushort_t* a = tnT + (size_t)b * S * C;
            const ushort_t* bb = gnT + (size_t)b * S * C;
            init_stats<<<16, 256, 0, stream>>>(colmax, colsum, S);
            gemm_mfma<<<dim3(S / 128, S / 128, 1), 256, 0, stream>>>(
                a, bb, sim, colmax, C, S, 0, 0, 0);
            colsum_kernel<<<dim3(S / 128, S / 128, 1), 256, 0, stream>>>(
                sim, colmax, colsum, S, 0, 0);
            rowmax_kernel<<<dim3(S / 16, 1), 256, 0, stream>>>(
                sim, colmax, colsum, acc + b, S, 0, 0);
        }
    }
    // ---- layer 1: C=512, S=1024, z-batched ----
    {
        const int C = 512, S = 1024;
        stats_kernel<<<dim3(S / 64, 4), 256, 0, stream>>>(gen4, tar4, mean, rg, rt, C, S);
        apply_kernel<<<dim3(S / 64, C / 64, 4), 256, 0, stream>>>(
            gen4, tar4, mean, rg, rt, gnT, tnT, C, S);
        init_stats<<<16, 256, 0, stream>>>(colmax, colsum, 4096);
        gemm_mfma<<<dim3(S / 128, S / 128, 4), 256, 0, stream>>>(
            tnT, gnT, sim, colmax, C, S, (size_t)S * C, (size_t)S * S, S);
        colsum_kernel<<<dim3(S / 128, S / 128, 4), 256, 0, stream>>>(
            sim, colmax, colsum, S, (size_t)S * S, S);
        rowmax_kernel<<<dim3(S / 16, 4), 256, 0, stream>>>(
            sim, colmax, colsum, acc + 4, S, (size_t)S * S, S);
    }
    finalize_kernel<<<1, 1, 0, stream>>>(acc, (float*)d_out);
}

// Round 4
// 439.808 us; speedup vs baseline: 4.0874x; 1.1720x over previous
//
#include <hip/hip_runtime.h>
#include <math.h>

// IDMRFLoss on MI355X — R3: global_load_lds(16B) MFMA gemm (global-side XOR
// swizzle), bf16 blocked sim, regridded stats.
//
// Layer 0 (relu3_2): B=4, C=256, S=4096, weight 1.0
// Layer 1 (relu4_2): B=4, C=512, S=1024, weight 2.0 (style + content)
//
// sim blocked bf16 layout (per 128x128 block at (by,bx)):
//   elem = (by*nQB+bx)*16384 + waveSlot*4096 + (t*4+u)*256 + quad*64 + lm*4 + r
//   p = by*128 + (slot&1)*64 + t*16 + quad*4 + r ; q = bx*128 + (slot>>1)*64 + u*16 + lm

#define MRF_EPS 1e-5f

typedef __attribute__((ext_vector_type(8))) short bf16x8;
typedef __attribute__((ext_vector_type(4))) float f32x4;
typedef unsigned short ushort_t;
struct __align__(8) ushort4_t { ushort_t x, y, z, w; };

__device__ __forceinline__ void atomicMaxFloat(float* addr, float v) {
    int* ai = (int*)addr;
    int old = __float_as_int(*(volatile float*)addr);
    while (__int_as_float(old) < v) {
        int assumed = old;
        old = atomicCAS(ai, assumed, __float_as_int(v));
        if (old == assumed) break;
    }
}

__device__ __forceinline__ ushort_t f2bf(float x) {
    unsigned u = __float_as_uint(x);
    u += 0x7FFFu + ((u >> 16) & 1u);
    return (ushort_t)(u >> 16);
}
__device__ __forceinline__ float bf2f(ushort_t u) {
    return __uint_as_float(((unsigned)u) << 16);
}

__device__ __forceinline__ void load_lds16(const ushort_t* g, ushort_t* l) {
    __builtin_amdgcn_global_load_lds(
        (const __attribute__((address_space(1))) void*)g,
        (__attribute__((address_space(3))) void*)l, 16, 0, 0);
}

// ---- stats: per position mean(tar), 1/||g-m||, 1/||t-m|| (single pass) ----
// grid (S/16, B), block 256: pq = tid&3 (position quad), cs = tid>>2 (channel stripe)
__global__ __launch_bounds__(256) void stats_kernel(
    const float* __restrict__ gen, const float* __restrict__ tar,
    float* __restrict__ mean, float* __restrict__ rg, float* __restrict__ rt,
    int C, int S) {
    int tid = threadIdx.x, pq = tid & 3, cs = tid >> 2;
    int b = blockIdx.y;
    int s0 = blockIdx.x * 16 + pq * 4;
    const float* g = gen + (size_t)b * C * S + s0;
    const float* t = tar + (size_t)b * C * S + s0;

    f32x4 st = {0.f, 0.f, 0.f, 0.f}, st2 = st, sg = st, sg2 = st;
    for (int c = cs; c < C; c += 64) {
        f32x4 tv = *(const f32x4*)(t + (size_t)c * S);
        f32x4 gv = *(const f32x4*)(g + (size_t)c * S);
        st += tv; st2 += tv * tv; sg += gv; sg2 += gv * gv;
    }
    __shared__ f32x4 red[4][4][64];
    __shared__ f32x4 red2[4][4][4];
    red[0][pq][cs] = st; red[1][pq][cs] = st2; red[2][pq][cs] = sg; red[3][pq][cs] = sg2;
    __syncthreads();
    if (tid < 64) {
        int s_ = tid >> 4, p_ = (tid >> 2) & 3, part = tid & 3;
        f32x4 s = red[s_][p_][part * 16];
#pragma unroll
        for (int j = 1; j < 16; j++) s += red[s_][p_][part * 16 + j];
        red2[s_][p_][part] = s;
    }
    __syncthreads();
    if (tid < 4) {
        f32x4 sts = red2[0][tid][0] + red2[0][tid][1] + red2[0][tid][2] + red2[0][tid][3];
        f32x4 st2s = red2[1][tid][0] + red2[1][tid][1] + red2[1][tid][2] + red2[1][tid][3];
        f32x4 sgs = red2[2][tid][0] + red2[2][tid][1] + red2[2][tid][2] + red2[2][tid][3];
        f32x4 sg2s = red2[3][tid][0] + red2[3][tid][1] + red2[3][tid][2] + red2[3][tid][3];
        f32x4 m, vrt, vrg;
        float invC = 1.f / (float)C;
#pragma unroll
        for (int e = 0; e < 4; e++) {
            float mm = sts[e] * invC;
            m[e] = mm;
            vrt[e] = rsqrtf(st2s[e] - mm * sts[e]);
            vrg[e] = rsqrtf(sg2s[e] - 2.f * mm * sgs[e] + mm * sts[e]);
        }
        int idx = b * S + blockIdx.x * 16 + tid * 4;
        *(f32x4*)(mean + idx) = m;
        *(f32x4*)(rt + idx) = vrt;
        *(f32x4*)(rg + idx) = vrg;
    }
}

// ---- apply: normalized transpose [C,S]fp32 -> [S,C]bf16, ushort4 writes ----
__global__ __launch_bounds__(256) void apply_kernel(
    const float* __restrict__ gen, const float* __restrict__ tar,
    const float* __restrict__ mean, const float* __restrict__ rg, const float* __restrict__ rt,
    ushort_t* __restrict__ gnT, ushort_t* __restrict__ tnT, int C, int S) {
    int tid = threadIdx.x;
    int b = blockIdx.z;
    int s0 = blockIdx.x * 64, c0 = blockIdx.y * 64;
    const float* g = gen + (size_t)b * C * S;
    const float* t = tar + (size_t)b * C * S;

    __shared__ float tg[64][65], tt[64][65];
    int tx = tid & 63, tw = tid >> 6;
#pragma unroll
    for (int i = 0; i < 16; i++) {
        int cl = tw * 16 + i;
        tg[cl][tx] = g[(size_t)(c0 + cl) * S + s0 + tx];
        tt[cl][tx] = t[(size_t)(c0 + cl) * S + s0 + tx];
    }
    __syncthreads();
    int cq = tid & 15;
#pragma unroll
    for (int j = 0; j < 4; j++) {
        int sl = (tid >> 4) * 4 + j;
        int idx = b * S + s0 + sl;
        float m = mean[idx], rgv = rg[idx], rtv = rt[idx];
        ushort4_t og, ot;
        og.x = f2bf((tg[cq * 4 + 0][sl] - m) * rgv);
        og.y = f2bf((tg[cq * 4 + 1][sl] - m) * rgv);
        og.z = f2bf((tg[cq * 4 + 2][sl] - m) * rgv);
        og.w = f2bf((tg[cq * 4 + 3][sl] - m) * rgv);
        ot.x = f2bf((tt[cq * 4 + 0][sl] - m) * rtv);
        ot.y = f2bf((tt[cq * 4 + 1][sl] - m) * rtv);
        ot.z = f2bf((tt[cq * 4 + 2][sl] - m) * rtv);
        ot.w = f2bf((tt[cq * 4 + 3][sl] - m) * rtv);
        size_t off = (size_t)idx * C + c0 + cq * 4;
        *(ushort4_t*)(gnT + off) = og;
        *(ushort4_t*)(tnT + off) = ot;
    }
}

__global__ void init_stats(float* __restrict__ colmax, float* __restrict__ colsum, int n) {
    int i = blockIdx.x * 256 + threadIdx.x;
    if (i < n) { colmax[i] = -INFINITY; colsum[i] = 0.f; }
}

__global__ void zero_acc(float* __restrict__ acc) {
    if (threadIdx.x < 8) acc[threadIdx.x] = 0.f;
}

// ---- MFMA GEMM: sim[p,q] = sum_k A[p,k]*B[q,k] (bf16 blocked store) + colmax ----
// 128x128 tile, BK=128 chunks, global_load_lds w16 with global-side XOR swizzle:
// LDS(row,pos16) = G(row, pos16 ^ (row&7)); frag read pos = u ^ (row&7) -> conflict-free.
template <int K>
__global__ __launch_bounds__(256) void gemm_mfma(
    const ushort_t* __restrict__ A, const ushort_t* __restrict__ B,
    ushort_t* __restrict__ sim, float* __restrict__ colmax,
    int S, size_t abStride, size_t simStride, int cmStride) {
    int z = blockIdx.z;
    A += (size_t)z * abStride; B += (size_t)z * abStride;
    sim += (size_t)z * simStride; colmax += (size_t)z * cmStride;

    __shared__ __align__(16) ushort_t As[128 * 128];  // 32 KB
    __shared__ __align__(16) ushort_t Bs[128 * 128];  // 32 KB

    const int tid = threadIdx.x;
    const int lane = tid & 63, wave = tid >> 6;
    const int wm = (wave & 1) * 64, wn = (wave >> 1) * 64;
    const int lm = lane & 15, quad = lane >> 4;
    const int p0 = blockIdx.y * 128, q0 = blockIdx.x * 128;

    f32x4 acc[4][4];
#pragma unroll
    for (int t = 0; t < 4; t++)
#pragma unroll
        for (int u = 0; u < 4; u++) acc[t][u] = (f32x4){0.f, 0.f, 0.f, 0.f};

    const int rowoff = lane >> 4, pos = lane & 15;
    const int kChunks = K / 128;
#pragma unroll
    for (int kc = 0; kc < kChunks; kc++) {
        if (kc > 0) __syncthreads();  // WAR: prior chunk's ds_reads done before DMA overwrite
        // stage 32KB+32KB: per wave 8 A + 8 B instrs, each 1KB (4 rows x 256B)
#pragma unroll
        for (int j = 0; j < 8; j++) {
            int R = wave * 32 + j * 4;
            int row = R + rowoff;
            int g = pos ^ (row & 7);
            load_lds16(A + (size_t)(p0 + row) * K + kc * 128 + g * 8, &As[R * 128]);
            load_lds16(B + (size_t)(q0 + row) * K + kc * 128 + g * 8, &Bs[R * 128]);
        }
        __syncthreads();  // drains vmcnt(0): staged data visible to all waves
#pragma unroll
        for (int ks = 0; ks < 4; ks++) {
            bf16x8 af[4], bfr[4];
#pragma unroll
            for (int t = 0; t < 4; t++) {
                int row = wm + t * 16 + lm;
                af[t] = *(const bf16x8*)&As[row * 128 + (((ks * 4 + quad) ^ (row & 7)) << 3)];
            }
#pragma unroll
            for (int u = 0; u < 4; u++) {
                int row = wn + u * 16 + lm;
                bfr[u] = *(const bf16x8*)&Bs[row * 128 + (((ks * 4 + quad) ^ (row & 7)) << 3)];
            }
#pragma unroll
            for (int t = 0; t < 4; t++)
#pragma unroll
                for (int u = 0; u < 4; u++)
                    acc[t][u] = __builtin_amdgcn_mfma_f32_16x16x32_bf16(af[t], bfr[u], acc[t][u], 0, 0, 0);
        }
    }

    // epilogue: round to bf16, blocked store (each (t,u): wave writes 512B contiguous)
    int nQB = S >> 7;
    size_t base = ((size_t)(blockIdx.y * nQB + blockIdx.x)) * 16384
                + (size_t)(wave * 4096 + quad * 64 + lm * 4);
    float cmax[4] = {-INFINITY, -INFINITY, -INFINITY, -INFINITY};
#pragma unroll
    for (int t = 0; t < 4; t++)
#pragma unroll
        for (int u = 0; u < 4; u++) {
            f32x4 v = acc[t][u];
            ushort4_t o;
            o.x = f2bf(v.x); o.y = f2bf(v.y); o.z = f2bf(v.z); o.w = f2bf(v.w);
            *(ushort4_t*)(sim + base + (t * 4 + u) * 256) = o;
            float mx = fmaxf(fmaxf(bf2f(o.x), bf2f(o.y)), fmaxf(bf2f(o.z), bf2f(o.w)));
            cmax[u] = fmaxf(cmax[u], mx);
        }
#pragma unroll
    for (int u = 0; u < 4; u++) {
        float m = cmax[u];
        m = fmaxf(m, __shfl_xor(m, 16, 64));
        m = fmaxf(m, __shfl_xor(m, 32, 64));
        if (lane < 16) atomicMaxFloat(colmax + q0 + wn + u * 16 + lane, m);
    }
}

// ---- column sums of dist (bf16 blocked reads) ----
__global__ __launch_bounds__(256) void colsum_kernel(
    const ushort_t* __restrict__ sim, const float* __restrict__ colmax,
    float* __restrict__ colsum, int S, size_t simStride, int cmStride) {
    int z = blockIdx.z;
    sim += (size_t)z * simStride; colmax += z * cmStride; colsum += z * cmStride;
    int tid = threadIdx.x, lane = tid & 63;
    int u = lane >> 4, lm = lane & 15;
    int sub = (tid >> 6) & 1, cg = tid >> 7;
    int bx = blockIdx.x, by = blockIdx.y;
    int nQB = S >> 7;
    int q = bx * 128 + cg * 64 + u * 16 + lm;
    float c1 = 1.f / ((1.f - colmax[q]) * 0.5f + MRF_EPS);
    float c0 = 2.f - c1;
    const ushort_t* base = sim + ((size_t)(by * nQB + bx)) * 16384
                         + (size_t)((sub | (cg << 1)) * 4096 + u * 256 + lm * 4);
    float s = 0.f;
#pragma unroll
    for (int t = 0; t < 4; t++)
#pragma unroll
        for (int quad = 0; quad < 4; quad++) {
            ushort4_t w = *(const ushort4_t*)(base + t * 1024 + quad * 64);
            s += __expf(c0 + c1 * bf2f(w.x)) + __expf(c0 + c1 * bf2f(w.y))
               + __expf(c0 + c1 * bf2f(w.z)) + __expf(c0 + c1 * bf2f(w.w));
        }
    atomicAdd(colsum + q, s);
}

// ---- row max of cs, fused partial sum ----
__global__ __launch_bounds__(256) void rowmax_kernel(
    const ushort_t* __restrict__ sim, const float* __restrict__ colmax,
    const float* __restrict__ colsum, float* __restrict__ acc, int S,
    size_t simStride, int cmStride) {
    int z = blockIdx.y;
    sim += (size_t)z * simStride; colmax += z * cmStride; colsum += z * cmStride;
    int wave = threadIdx.x >> 6, lane = threadIdx.x & 63;
    int g = blockIdx.x * 4 + wave;
    int by = g >> 5, rem = g & 31;
    int sub = rem >> 4, t = (rem >> 2) & 3, quad = rem & 3;
    int u = lane >> 4, lm = lane & 15;
    int nQB = S >> 7;
    f32x4 m = {-INFINITY, -INFINITY, -INFINITY, -INFINITY};
    for (int bx = 0; bx < nQB; bx++) {
#pragma unroll
        for (int cg = 0; cg < 2; cg++) {
            int q = bx * 128 + cg * 64 + u * 16 + lm;
            float c1 = 1.f / ((1.f - colmax[q]) * 0.5f + MRF_EPS);
            float c0 = 2.f - c1;
            float rcs = 1.f / colsum[q];
            const ushort_t* ptr = sim + ((size_t)(by * nQB + bx)) * 16384
                                + (size_t)((sub | (cg << 1)) * 4096 + (t * 4 + u) * 256 + quad * 64 + lm * 4);
            ushort4_t w = *(const ushort4_t*)ptr;
            m[0] = fmaxf(m[0], __expf(c0 + c1 * bf2f(w.x)) * rcs);
            m[1] = fmaxf(m[1], __expf(c0 + c1 * bf2f(w.y)) * rcs);
            m[2] = fmaxf(m[2], __expf(c0 + c1 * bf2f(w.z)) * rcs);
            m[3] = fmaxf(m[3], __expf(c0 + c1 * bf2f(w.w)) * rcs);
        }
    }
#pragma unroll
    for (int off = 32; off >= 1; off >>= 1)
#pragma unroll
        for (int e = 0; e < 4; e++)
            m[e] = fmaxf(m[e], __shfl_xor(m[e], off, 64));
    __shared__ float partial[4];
    if (lane == 0) partial[wave] = m[0] + m[1] + m[2] + m[3];
    __syncthreads();
    if (threadIdx.x == 0)
        atomicAdd(acc + z, partial[0] + partial[1] + partial[2] + partial[3]);
}

__global__ void finalize_kernel(const float* __restrict__ acc, float* __restrict__ out) {
    float loss = 0.f;
    for (int b = 0; b < 4; b++) loss += -logf(acc[b] * (1.f / 4096.f));
    for (int b = 0; b < 4; b++) loss += -2.f * logf(acc[4 + b] * (1.f / 1024.f));
    out[0] = loss;
}

extern "C" void kernel_launch(void* const* d_in, const int* in_sizes, int n_in,
                              void* d_out, int out_size, void* d_ws, size_t ws_size,
                              hipStream_t stream) {
    const float* gen3 = (const float*)d_in[0];
    const float* tar3 = (const float*)d_in[1];
    const float* gen4 = (const float*)d_in[2];
    const float* tar4 = (const float*)d_in[3];

    float* ws = (float*)d_ws;
    ushort_t* sim = (ushort_t*)ws;           // 16.78M ushort (layer4: 4 x 1M)
    float* mean = ws + 8388608;              // 16384
    float* rg = mean + 16384;                // 16384
    float* rt = rg + 16384;                  // 16384
    float* colmax = rt + 16384;              // 16384 (4 z-slots)
    float* colsum = colmax + 16384;          // 16384
    float* acc = colsum + 16384;             // 8 (+pad)
    ushort_t* gnT = (ushort_t*)(acc + 64);   // 4*4096*256 bf16
    ushort_t* tnT = gnT + 4 * 4096 * 256;    // total ~51 MB

    zero_acc<<<1, 64, 0, stream>>>(acc);

    // ---- layer 0: C=256, S=4096, per-batch sim ----
    {
        const int C = 256, S = 4096;
        stats_kernel<<<dim3(S / 16, 4), 256, 0, stream>>>(gen3, tar3, mean, rg, rt, C, S);
        apply_kernel<<<dim3(S / 64, C / 64, 4), 256, 0, stream>>>(
            gen3, tar3, mean, rg, rt, gnT, tnT, C, S);
        for (int b = 0; b < 4; b++) {
            const ushort_t* a = tnT + (size_t)b * S * C;
            const ushort_t* bb = gnT + (size_t)b * S * C;
            init_stats<<<16, 256, 0, stream>>>(colmax, colsum, S);
            gemm_mfma<256><<<dim3(S / 128, S / 128, 1), 256, 0, stream>>>(
                a, bb, sim, colmax, S, 0, 0, 0);
            colsum_kernel<<<dim3(S / 128, S / 128, 1), 256, 0, stream>>>(
                sim, colmax, colsum, S, 0, 0);
            rowmax_kernel<<<dim3(S / 16, 1), 256, 0, stream>>>(
                sim, colmax, colsum, acc + b, S, 0, 0);
        }
    }
    // ---- layer 1: C=512, S=1024, z-batched ----
    {
        const int C = 512, S = 1024;
        stats_kernel<<<dim3(S / 16, 4), 256, 0, stream>>>(gen4, tar4, mean, rg, rt, C, S);
        apply_kernel<<<dim3(S / 64, C / 64, 4), 256, 0, stream>>>(
            gen4, tar4, mean, rg, rt, gnT, tnT, C, S);
        init_stats<<<16, 256, 0, stream>>>(colmax, colsum, 4096);
        gemm_mfma<512><<<dim3(S / 128, S / 128, 4), 256, 0, stream>>>(
            tnT, gnT, sim, colmax, S, (size_t)S * C, (size_t)S * S, S);
        colsum_kernel<<<dim3(S / 128, S / 128, 4), 256, 0, stream>>>(
            sim, colmax, colsum, S, (size_t)S * S, S);
        rowmax_kernel<<<dim3(S / 16, 4), 256, 0, stream>>>(
            sim, colmax, colsum, acc + 4, S, (size_t)S * S, S);
    }
    finalize_kernel<<<1, 1, 0, stream>>>(acc, (float*)d_out);
}

// Round 5
// 438.387 us; speedup vs baseline: 4.1007x; 1.0032x over previous
//
#include <hip/hip_runtime.h>
#include <math.h>

// IDMRFLoss on MI355X — R5: LDS-free MFMA gemm reading a pre-swizzled
// MFMA-native global layout (written by apply), direct global->VGPR frags,
// zero barriers in the K-loop.
//
// Layer 0 (relu3_2): B=4, C=256, S=4096, weight 1.0
// Layer 1 (relu4_2): B=4, C=512, S=1024, weight 2.0 (style + content)
//
// Swizzled operand layout (per batch, matrix [S][K] bf16):
//   elem(row,k) at ((row>>4)*(K/8) + (k>>3))*128 + (row&15)*8 + (k&7)
//   -> an MFMA A/B fragment load (16 rows x 8 k, 4 quads) is 4x256B contiguous.
//
// sim blocked bf16 layout (per 128x128 block at (by,bx)):
//   elem = (by*nQB+bx)*16384 + waveSlot*4096 + (t*4+u)*256 + quad*64 + lm*4 + r
//   p = by*128 + (slot&1)*64 + t*16 + quad*4 + r ; q = bx*128 + (slot>>1)*64 + u*16 + lm

#define MRF_EPS 1e-5f

typedef __attribute__((ext_vector_type(8))) short bf16x8;
typedef __attribute__((ext_vector_type(4))) float f32x4;
typedef unsigned short ushort_t;
struct __align__(8) ushort4_t { ushort_t x, y, z, w; };
struct __align__(16) ushort8_t { ushort_t v[8]; };

__device__ __forceinline__ void atomicMaxFloat(float* addr, float v) {
    int* ai = (int*)addr;
    int old = __float_as_int(*(volatile float*)addr);
    while (__int_as_float(old) < v) {
        int assumed = old;
        old = atomicCAS(ai, assumed, __float_as_int(v));
        if (old == assumed) break;
    }
}

__device__ __forceinline__ ushort_t f2bf(float x) {
    unsigned u = __float_as_uint(x);
    u += 0x7FFFu + ((u >> 16) & 1u);
    return (ushort_t)(u >> 16);
}
__device__ __forceinline__ float bf2f(ushort_t u) {
    return __uint_as_float(((unsigned)u) << 16);
}

// ---- stats: per position mean(tar), 1/||g-m||, 1/||t-m|| (single pass) ----
// grid (S/16, B), block 256: pq = tid&3 (position quad), cs = tid>>2 (channel stripe)
__global__ __launch_bounds__(256) void stats_kernel(
    const float* __restrict__ gen, const float* __restrict__ tar,
    float* __restrict__ mean, float* __restrict__ rg, float* __restrict__ rt,
    int C, int S) {
    int tid = threadIdx.x, pq = tid & 3, cs = tid >> 2;
    int b = blockIdx.y;
    int s0 = blockIdx.x * 16 + pq * 4;
    const float* g = gen + (size_t)b * C * S + s0;
    const float* t = tar + (size_t)b * C * S + s0;

    f32x4 st = {0.f, 0.f, 0.f, 0.f}, st2 = st, sg = st, sg2 = st;
    for (int c = cs; c < C; c += 64) {
        f32x4 tv = *(const f32x4*)(t + (size_t)c * S);
        f32x4 gv = *(const f32x4*)(g + (size_t)c * S);
        st += tv; st2 += tv * tv; sg += gv; sg2 += gv * gv;
    }
    __shared__ f32x4 red[4][4][64];
    __shared__ f32x4 red2[4][4][4];
    red[0][pq][cs] = st; red[1][pq][cs] = st2; red[2][pq][cs] = sg; red[3][pq][cs] = sg2;
    __syncthreads();
    if (tid < 64) {
        int s_ = tid >> 4, p_ = (tid >> 2) & 3, part = tid & 3;
        f32x4 s = red[s_][p_][part * 16];
#pragma unroll
        for (int j = 1; j < 16; j++) s += red[s_][p_][part * 16 + j];
        red2[s_][p_][part] = s;
    }
    __syncthreads();
    if (tid < 4) {
        f32x4 sts = red2[0][tid][0] + red2[0][tid][1] + red2[0][tid][2] + red2[0][tid][3];
        f32x4 st2s = red2[1][tid][0] + red2[1][tid][1] + red2[1][tid][2] + red2[1][tid][3];
        f32x4 sgs = red2[2][tid][0] + red2[2][tid][1] + red2[2][tid][2] + red2[2][tid][3];
        f32x4 sg2s = red2[3][tid][0] + red2[3][tid][1] + red2[3][tid][2] + red2[3][tid][3];
        f32x4 m, vrt, vrg;
        float invC = 1.f / (float)C;
#pragma unroll
        for (int e = 0; e < 4; e++) {
            float mm = sts[e] * invC;
            m[e] = mm;
            vrt[e] = rsqrtf(st2s[e] - mm * sts[e]);
            vrg[e] = rsqrtf(sg2s[e] - 2.f * mm * sgs[e] + mm * sts[e]);
        }
        int idx = b * S + blockIdx.x * 16 + tid * 4;
        *(f32x4*)(mean + idx) = m;
        *(f32x4*)(rt + idx) = vrt;
        *(f32x4*)(rg + idx) = vrg;
    }
}

// ---- apply: normalize + transpose [C,S]fp32 -> swizzled MFMA layout bf16 ----
// grid (S/64, C/64, B), block 256. Normalization done pre-LDS (bf16 in LDS).
__global__ __launch_bounds__(256) void apply_kernel(
    const float* __restrict__ gen, const float* __restrict__ tar,
    const float* __restrict__ mean, const float* __restrict__ rg, const float* __restrict__ rt,
    ushort_t* __restrict__ gnT, ushort_t* __restrict__ tnT, int C, int S) {
    int tid = threadIdx.x;
    int b = blockIdx.z;
    int s0 = blockIdx.x * 64, c0 = blockIdx.y * 64;
    const float* g = gen + (size_t)b * C * S;
    const float* t = tar + (size_t)b * C * S;
    int tx = tid & 63, tw = tid >> 6;
    int sidx = b * S + s0 + tx;
    float m = mean[sidx], rgv = rg[sidx], rtv = rt[sidx];

    __shared__ ushort_t tg[64][72], tt_[64][72];   // [s][c], 144B row = 16B aligned
#pragma unroll
    for (int i = 0; i < 16; i++) {
        int cl = tw * 16 + i;
        float gv = g[(size_t)(c0 + cl) * S + s0 + tx];
        float tv = t[(size_t)(c0 + cl) * S + s0 + tx];
        tg[tx][cl] = f2bf((gv - m) * rgv);
        tt_[tx][cl] = f2bf((tv - m) * rtv);
    }
    __syncthreads();
    int KC = C >> 3;
#pragma unroll
    for (int j = 0; j < 2; j++) {
        int p = j * 256 + tid;
        int s = p & 63, ch = p >> 6;      // s-lane, chunk 0..7
        int row = s0 + s;
        int r16 = row >> 4, lm = row & 15;
        size_t off = (size_t)b * S * C + (((size_t)r16 * KC + (c0 >> 3) + ch) * 16 + lm) * 8;
        *(ushort8_t*)(gnT + off) = *(const ushort8_t*)&tg[s][ch * 8];
        *(ushort8_t*)(tnT + off) = *(const ushort8_t*)&tt_[s][ch * 8];
    }
}

__global__ void init_stats(float* __restrict__ colmax, float* __restrict__ colsum, int n) {
    int i = blockIdx.x * 256 + threadIdx.x;
    if (i < n) { colmax[i] = -INFINITY; colsum[i] = 0.f; }
}

__global__ void zero_acc(float* __restrict__ acc) {
    if (threadIdx.x < 8) acc[threadIdx.x] = 0.f;
}

// ---- MFMA GEMM, LDS-free: frags loaded straight from swizzled global ----
// 128x128 tile, 4 waves x (64x64). No barriers; manual 2-deep frag pipeline.
template <int K>
__global__ __launch_bounds__(256) void gemm_mfma(
    const ushort_t* __restrict__ A, const ushort_t* __restrict__ B,
    ushort_t* __restrict__ sim, float* __restrict__ colmax,
    int S, size_t abStride, size_t simStride, int cmStride) {
    int z = blockIdx.z;
    A += (size_t)z * abStride; B += (size_t)z * abStride;
    sim += (size_t)z * simStride; colmax += (size_t)z * cmStride;

    const int tid = threadIdx.x;
    const int lane = tid & 63, wave = tid >> 6;
    const int wm = (wave & 1) * 64, wn = (wave >> 1) * 64;
    const int lm = lane & 15, quad = lane >> 4;
    const int p0 = blockIdx.y * 128, q0 = blockIdx.x * 128;

    constexpr int KC = K / 8;     // 16B chunks per row
    constexpr int KS = K / 32;    // MFMA k-steps (8 or 16, even)

    // lane-fixed bases: + (t*KC + ks*4)*128 selects fragment
    const ushort_t* Ab = A + ((size_t)((p0 + wm) >> 4) * KC + quad) * 128 + lm * 8;
    const ushort_t* Bb = B + ((size_t)((q0 + wn) >> 4) * KC + quad) * 128 + lm * 8;

    f32x4 acc[4][4];
#pragma unroll
    for (int t = 0; t < 4; t++)
#pragma unroll
        for (int u = 0; u < 4; u++) acc[t][u] = (f32x4){0.f, 0.f, 0.f, 0.f};

    bf16x8 a0[4], b0[4], a1[4], b1[4];
#pragma unroll
    for (int t = 0; t < 4; t++) {
        a0[t] = *(const bf16x8*)(Ab + (size_t)(t * KC) * 128);
        b0[t] = *(const bf16x8*)(Bb + (size_t)(t * KC) * 128);
    }
#pragma unroll
    for (int ks = 0; ks < KS; ks += 2) {
        // prefetch ks+1
#pragma unroll
        for (int t = 0; t < 4; t++) {
            a1[t] = *(const bf16x8*)(Ab + (size_t)(t * KC + (ks + 1) * 4) * 128);
            b1[t] = *(const bf16x8*)(Bb + (size_t)(t * KC + (ks + 1) * 4) * 128);
        }
#pragma unroll
        for (int t = 0; t < 4; t++)
#pragma unroll
            for (int u = 0; u < 4; u++)
                acc[t][u] = __builtin_amdgcn_mfma_f32_16x16x32_bf16(a0[t], b0[u], acc[t][u], 0, 0, 0);
        if (ks + 2 < KS) {
#pragma unroll
            for (int t = 0; t < 4; t++) {
                a0[t] = *(const bf16x8*)(Ab + (size_t)(t * KC + (ks + 2) * 4) * 128);
                b0[t] = *(const bf16x8*)(Bb + (size_t)(t * KC + (ks + 2) * 4) * 128);
            }
        }
#pragma unroll
        for (int t = 0; t < 4; t++)
#pragma unroll
            for (int u = 0; u < 4; u++)
                acc[t][u] = __builtin_amdgcn_mfma_f32_16x16x32_bf16(a1[t], b1[u], acc[t][u], 0, 0, 0);
    }

    // epilogue: round to bf16, blocked store + colmax
    int nQB = S >> 7;
    size_t base = ((size_t)(blockIdx.y * nQB + blockIdx.x)) * 16384
                + (size_t)(wave * 4096 + quad * 64 + lm * 4);
    float cmax[4] = {-INFINITY, -INFINITY, -INFINITY, -INFINITY};
#pragma unroll
    for (int t = 0; t < 4; t++)
#pragma unroll
        for (int u = 0; u < 4; u++) {
            f32x4 v = acc[t][u];
            ushort4_t o;
            o.x = f2bf(v.x); o.y = f2bf(v.y); o.z = f2bf(v.z); o.w = f2bf(v.w);
            *(ushort4_t*)(sim + base + (t * 4 + u) * 256) = o;
            float mx = fmaxf(fmaxf(bf2f(o.x), bf2f(o.y)), fmaxf(bf2f(o.z), bf2f(o.w)));
            cmax[u] = fmaxf(cmax[u], mx);
        }
#pragma unroll
    for (int u = 0; u < 4; u++) {
        float m = cmax[u];
        m = fmaxf(m, __shfl_xor(m, 16, 64));
        m = fmaxf(m, __shfl_xor(m, 32, 64));
        if (lane < 16) atomicMaxFloat(colmax + q0 + wn + u * 16 + lane, m);
    }
}

// ---- column sums of dist (bf16 blocked reads) ----
__global__ __launch_bounds__(256) void colsum_kernel(
    const ushort_t* __restrict__ sim, const float* __restrict__ colmax,
    float* __restrict__ colsum, int S, size_t simStride, int cmStride) {
    int z = blockIdx.z;
    sim += (size_t)z * simStride; colmax += z * cmStride; colsum += z * cmStride;
    int tid = threadIdx.x, lane = tid & 63;
    int u = lane >> 4, lm = lane & 15;
    int sub = (tid >> 6) & 1, cg = tid >> 7;
    int bx = blockIdx.x, by = blockIdx.y;
    int nQB = S >> 7;
    int q = bx * 128 + cg * 64 + u * 16 + lm;
    float c1 = 1.f / ((1.f - colmax[q]) * 0.5f + MRF_EPS);
    float c0 = 2.f - c1;
    const ushort_t* base = sim + ((size_t)(by * nQB + bx)) * 16384
                         + (size_t)((sub | (cg << 1)) * 4096 + u * 256 + lm * 4);
    float s = 0.f;
#pragma unroll
    for (int t = 0; t < 4; t++)
#pragma unroll
        for (int quad = 0; quad < 4; quad++) {
            ushort4_t w = *(const ushort4_t*)(base + t * 1024 + quad * 64);
            s += __expf(c0 + c1 * bf2f(w.x)) + __expf(c0 + c1 * bf2f(w.y))
               + __expf(c0 + c1 * bf2f(w.z)) + __expf(c0 + c1 * bf2f(w.w));
        }
    atomicAdd(colsum + q, s);
}

// ---- row max of cs, fused partial sum ----
__global__ __launch_bounds__(256) void rowmax_kernel(
    const ushort_t* __restrict__ sim, const float* __restrict__ colmax,
    const float* __restrict__ colsum, float* __restrict__ acc, int S,
    size_t simStride, int cmStride) {
    int z = blockIdx.y;
    sim += (size_t)z * simStride; colmax += z * cmStride; colsum += z * cmStride;
    int wave = threadIdx.x >> 6, lane = threadIdx.x & 63;
    int g = blockIdx.x * 4 + wave;
    int by = g >> 5, rem = g & 31;
    int sub = rem >> 4, t = (rem >> 2) & 3, quad = rem & 3;
    int u = lane >> 4, lm = lane & 15;
    int nQB = S >> 7;
    f32x4 m = {-INFINITY, -INFINITY, -INFINITY, -INFINITY};
    for (int bx = 0; bx < nQB; bx++) {
#pragma unroll
        for (int cg = 0; cg < 2; cg++) {
            int q = bx * 128 + cg * 64 + u * 16 + lm;
            float c1 = 1.f / ((1.f - colmax[q]) * 0.5f + MRF_EPS);
            float c0 = 2.f - c1;
            float rcs = 1.f / colsum[q];
            const ushort_t* ptr = sim + ((size_t)(by * nQB + bx)) * 16384
                                + (size_t)((sub | (cg << 1)) * 4096 + (t * 4 + u) * 256 + quad * 64 + lm * 4);
            ushort4_t w = *(const ushort4_t*)ptr;
            m[0] = fmaxf(m[0], __expf(c0 + c1 * bf2f(w.x)) * rcs);
            m[1] = fmaxf(m[1], __expf(c0 + c1 * bf2f(w.y)) * rcs);
            m[2] = fmaxf(m[2], __expf(c0 + c1 * bf2f(w.z)) * rcs);
            m[3] = fmaxf(m[3], __expf(c0 + c1 * bf2f(w.w)) * rcs);
        }
    }
#pragma unroll
    for (int off = 32; off >= 1; off >>= 1)
#pragma unroll
        for (int e = 0; e < 4; e++)
            m[e] = fmaxf(m[e], __shfl_xor(m[e], off, 64));
    __shared__ float partial[4];
    if (lane == 0) partial[wave] = m[0] + m[1] + m[2] + m[3];
    __syncthreads();
    if (threadIdx.x == 0)
        atomicAdd(acc + z, partial[0] + partial[1] + partial[2] + partial[3]);
}

__global__ void finalize_kernel(const float* __restrict__ acc, float* __restrict__ out) {
    float loss = 0.f;
    for (int b = 0; b < 4; b++) loss += -logf(acc[b] * (1.f / 4096.f));
    for (int b = 0; b < 4; b++) loss += -2.f * logf(acc[4 + b] * (1.f / 1024.f));
    out[0] = loss;
}

extern "C" void kernel_launch(void* const* d_in, const int* in_sizes, int n_in,
                              void* d_out, int out_size, void* d_ws, size_t ws_size,
                              hipStream_t stream) {
    const float* gen3 = (const float*)d_in[0];
    const float* tar3 = (const float*)d_in[1];
    const float* gen4 = (const float*)d_in[2];
    const float* tar4 = (const float*)d_in[3];

    float* ws = (float*)d_ws;
    ushort_t* sim = (ushort_t*)ws;           // 16.78M ushort (layer4: 4 x 1M)
    float* mean = ws + 8388608;              // 16384
    float* rg = mean + 16384;                // 16384
    float* rt = rg + 16384;                  // 16384
    float* colmax = rt + 16384;              // 16384 (4 z-slots)
    float* colsum = colmax + 16384;          // 16384
    float* acc = colsum + 16384;             // 8 (+pad)
    ushort_t* gnT = (ushort_t*)(acc + 64);   // 4*4096*256 bf16 (swizzled)
    ushort_t* tnT = gnT + 4 * 4096 * 256;    // total ~51 MB

    zero_acc<<<1, 64, 0, stream>>>(acc);

    // ---- layer 0: C=256, S=4096, per-batch sim ----
    {
        const int C = 256, S = 4096;
        stats_kernel<<<dim3(S / 16, 4), 256, 0, stream>>>(gen3, tar3, mean, rg, rt, C, S);
        apply_kernel<<<dim3(S / 64, C / 64, 4), 256, 0, stream>>>(
            gen3, tar3, mean, rg, rt, gnT, tnT, C, S);
        for (int b = 0; b < 4; b++) {
            const ushort_t* a = tnT + (size_t)b * S * C;
            const ushort_t* bb = gnT + (size_t)b * S * C;
            init_stats<<<16, 256, 0, stream>>>(colmax, colsum, S);
            gemm_mfma<256><<<dim3(S / 128, S / 128, 1), 256, 0, stream>>>(
                a, bb, sim, colmax, S, 0, 0, 0);
            colsum_kernel<<<dim3(S / 128, S / 128, 1), 256, 0, stream>>>(
                sim, colmax, colsum, S, 0, 0);
            rowmax_kernel<<<dim3(S / 16, 1), 256, 0, stream>>>(
                sim, colmax, colsum, acc + b, S, 0, 0);
        }
    }
    // ---- layer 1: C=512, S=1024, z-batched ----
    {
        const int C = 512, S = 1024;
        stats_kernel<<<dim3(S / 16, 4), 256, 0, stream>>>(gen4, tar4, mean, rg, rt, C, S);
        apply_kernel<<<dim3(S / 64, C / 64, 4), 256, 0, stream>>>(
            gen4, tar4, mean, rg, rt, gnT, tnT, C, S);
        init_stats<<<16, 256, 0, stream>>>(colmax, colsum, 4096);
        gemm_mfma<512><<<dim3(S / 128, S / 128, 4), 256, 0, stream>>>(
            tnT, gnT, sim, colmax, S, (size_t)S * C, (size_t)S * S, S);
        colsum_kernel<<<dim3(S / 128, S / 128, 4), 256, 0, stream>>>(
            sim, colmax, colsum, S, (size_t)S * S, S);
        rowmax_kernel<<<dim3(S / 16, 4), 256, 0, stream>>>(
            sim, colmax, colsum, acc + 4, S, (size_t)S * S, S);
    }
    finalize_kernel<<<1, 1, 0, stream>>>(acc, (float*)d_out);
}

// Round 6
// 314.657 us; speedup vs baseline: 5.7131x; 1.3932x over previous
//
#include <hip/hip_runtime.h>
#include <math.h>

// IDMRFLoss on MI355X — R6: no-atomic colmax (partials + reduce), coef
// precompute/fold (rowmax = fma+exp only), z-batched layer3 (2 rounds x 2).
//
// Layer 0 (relu3_2): B=4, C=256, S=4096, weight 1.0
// Layer 1 (relu4_2): B=4, C=512, S=1024, weight 2.0 (style + content)
//
// Swizzled operand layout (per batch-slot, matrix [S][K] bf16):
//   elem(row,k) at ((row>>4)*(K/8) + (k>>3))*128 + (row&15)*8 + (k&7)
// sim blocked bf16 layout (per 128x128 block at (by,bx)):
//   elem = (by*nQB+bx)*16384 + wave*4096 + (t*4+u)*256 + quad*64 + lm*4 + r
//   p = by*128 + (wave&1)*64 + t*16 + quad*4 + r ; q = bx*128 + (wave>>1)*64 + u*16 + lm

#define MRF_EPS 1e-5f

typedef __attribute__((ext_vector_type(8))) short bf16x8;
typedef __attribute__((ext_vector_type(4))) float f32x4;
typedef unsigned short ushort_t;
struct __align__(8) ushort4_t { ushort_t x, y, z, w; };
struct __align__(16) ushort8_t { ushort_t v[8]; };

__device__ __forceinline__ ushort_t f2bf(float x) {
    unsigned u = __float_as_uint(x);
    u += 0x7FFFu + ((u >> 16) & 1u);
    return (ushort_t)(u >> 16);
}
__device__ __forceinline__ float bf2f(ushort_t u) {
    return __uint_as_float(((unsigned)u) << 16);
}

// ---- stats: per position mean(tar), 1/||g-m||, 1/||t-m|| (single pass) ----
__global__ __launch_bounds__(256) void stats_kernel(
    const float* __restrict__ gen, const float* __restrict__ tar,
    float* __restrict__ mean, float* __restrict__ rg, float* __restrict__ rt,
    int C, int S) {
    int tid = threadIdx.x, pq = tid & 3, cs = tid >> 2;
    int b = blockIdx.y;
    int s0 = blockIdx.x * 16 + pq * 4;
    const float* g = gen + (size_t)b * C * S + s0;
    const float* t = tar + (size_t)b * C * S + s0;

    f32x4 st = {0.f, 0.f, 0.f, 0.f}, st2 = st, sg = st, sg2 = st;
    for (int c = cs; c < C; c += 64) {
        f32x4 tv = *(const f32x4*)(t + (size_t)c * S);
        f32x4 gv = *(const f32x4*)(g + (size_t)c * S);
        st += tv; st2 += tv * tv; sg += gv; sg2 += gv * gv;
    }
    __shared__ f32x4 red[4][4][64];
    __shared__ f32x4 red2[4][4][4];
    red[0][pq][cs] = st; red[1][pq][cs] = st2; red[2][pq][cs] = sg; red[3][pq][cs] = sg2;
    __syncthreads();
    if (tid < 64) {
        int s_ = tid >> 4, p_ = (tid >> 2) & 3, part = tid & 3;
        f32x4 s = red[s_][p_][part * 16];
#pragma unroll
        for (int j = 1; j < 16; j++) s += red[s_][p_][part * 16 + j];
        red2[s_][p_][part] = s;
    }
    __syncthreads();
    if (tid < 4) {
        f32x4 sts = red2[0][tid][0] + red2[0][tid][1] + red2[0][tid][2] + red2[0][tid][3];
        f32x4 st2s = red2[1][tid][0] + red2[1][tid][1] + red2[1][tid][2] + red2[1][tid][3];
        f32x4 sgs = red2[2][tid][0] + red2[2][tid][1] + red2[2][tid][2] + red2[2][tid][3];
        f32x4 sg2s = red2[3][tid][0] + red2[3][tid][1] + red2[3][tid][2] + red2[3][tid][3];
        f32x4 m, vrt, vrg;
        float invC = 1.f / (float)C;
#pragma unroll
        for (int e = 0; e < 4; e++) {
            float mm = sts[e] * invC;
            m[e] = mm;
            vrt[e] = rsqrtf(st2s[e] - mm * sts[e]);
            vrg[e] = rsqrtf(sg2s[e] - 2.f * mm * sgs[e] + mm * sts[e]);
        }
        int idx = b * S + blockIdx.x * 16 + tid * 4;
        *(f32x4*)(mean + idx) = m;
        *(f32x4*)(rt + idx) = vrt;
        *(f32x4*)(rg + idx) = vrg;
    }
}

// ---- apply: normalize + transpose -> swizzled MFMA layout bf16 (slot z) ----
__global__ __launch_bounds__(256) void apply_kernel(
    const float* __restrict__ gen, const float* __restrict__ tar,
    const float* __restrict__ mean, const float* __restrict__ rg, const float* __restrict__ rt,
    ushort_t* __restrict__ gnT, ushort_t* __restrict__ tnT, int C, int S, int batchBase) {
    int tid = threadIdx.x;
    int slot = blockIdx.z, b = batchBase + slot;
    int s0 = blockIdx.x * 64, c0 = blockIdx.y * 64;
    const float* g = gen + (size_t)b * C * S;
    const float* t = tar + (size_t)b * C * S;
    int tx = tid & 63, tw = tid >> 6;
    int sidx = b * S + s0 + tx;
    float m = mean[sidx], rgv = rg[sidx], rtv = rt[sidx];

    __shared__ ushort_t tg[64][72], tt_[64][72];
#pragma unroll
    for (int i = 0; i < 16; i++) {
        int cl = tw * 16 + i;
        float gv = g[(size_t)(c0 + cl) * S + s0 + tx];
        float tv = t[(size_t)(c0 + cl) * S + s0 + tx];
        tg[tx][cl] = f2bf((gv - m) * rgv);
        tt_[tx][cl] = f2bf((tv - m) * rtv);
    }
    __syncthreads();
    int KC = C >> 3;
#pragma unroll
    for (int j = 0; j < 2; j++) {
        int p = j * 256 + tid;
        int s = p & 63, ch = p >> 6;
        int row = s0 + s;
        int r16 = row >> 4, lm = row & 15;
        size_t off = (size_t)slot * S * C + (((size_t)r16 * KC + (c0 >> 3) + ch) * 16 + lm) * 8;
        *(ushort8_t*)(gnT + off) = *(const ushort8_t*)&tg[s][ch * 8];
        *(ushort8_t*)(tnT + off) = *(const ushort8_t*)&tt_[s][ch * 8];
    }
}

__global__ void init_colsum(float* __restrict__ colsum, int n) {
    int i = blockIdx.x * 256 + threadIdx.x;
    if (i < n) colsum[i] = 0.f;
}

__global__ void zero_acc(float* __restrict__ acc) {
    if (threadIdx.x < 8) acc[threadIdx.x] = 0.f;
}

// ---- MFMA GEMM, LDS-free, no atomics: sim + colmax partials ----
template <int K>
__global__ __launch_bounds__(256) void gemm_mfma(
    const ushort_t* __restrict__ A, const ushort_t* __restrict__ B,
    ushort_t* __restrict__ sim, float* __restrict__ cmPart,
    int S, size_t abStride, size_t simStride, size_t cmStride) {
    int z = blockIdx.z;
    A += (size_t)z * abStride; B += (size_t)z * abStride;
    sim += (size_t)z * simStride; cmPart += (size_t)z * cmStride;

    const int tid = threadIdx.x;
    const int lane = tid & 63, wave = tid >> 6;
    const int wm = (wave & 1) * 64, wn = (wave >> 1) * 64;
    const int lm = lane & 15, quad = lane >> 4;
    const int p0 = blockIdx.y * 128, q0 = blockIdx.x * 128;

    constexpr int KC = K / 8;
    constexpr int KS = K / 32;

    const ushort_t* Ab = A + ((size_t)((p0 + wm) >> 4) * KC + quad) * 128 + lm * 8;
    const ushort_t* Bb = B + ((size_t)((q0 + wn) >> 4) * KC + quad) * 128 + lm * 8;

    f32x4 acc[4][4];
#pragma unroll
    for (int t = 0; t < 4; t++)
#pragma unroll
        for (int u = 0; u < 4; u++) acc[t][u] = (f32x4){0.f, 0.f, 0.f, 0.f};

    bf16x8 a0[4], b0[4], a1[4], b1[4];
#pragma unroll
    for (int t = 0; t < 4; t++) {
        a0[t] = *(const bf16x8*)(Ab + (size_t)(t * KC) * 128);
        b0[t] = *(const bf16x8*)(Bb + (size_t)(t * KC) * 128);
    }
#pragma unroll
    for (int ks = 0; ks < KS; ks += 2) {
#pragma unroll
        for (int t = 0; t < 4; t++) {
            a1[t] = *(const bf16x8*)(Ab + (size_t)(t * KC + (ks + 1) * 4) * 128);
            b1[t] = *(const bf16x8*)(Bb + (size_t)(t * KC + (ks + 1) * 4) * 128);
        }
#pragma unroll
        for (int t = 0; t < 4; t++)
#pragma unroll
            for (int u = 0; u < 4; u++)
                acc[t][u] = __builtin_amdgcn_mfma_f32_16x16x32_bf16(a0[t], b0[u], acc[t][u], 0, 0, 0);
        if (ks + 2 < KS) {
#pragma unroll
            for (int t = 0; t < 4; t++) {
                a0[t] = *(const bf16x8*)(Ab + (size_t)(t * KC + (ks + 2) * 4) * 128);
                b0[t] = *(const bf16x8*)(Bb + (size_t)(t * KC + (ks + 2) * 4) * 128);
            }
        }
#pragma unroll
        for (int t = 0; t < 4; t++)
#pragma unroll
            for (int u = 0; u < 4; u++)
                acc[t][u] = __builtin_amdgcn_mfma_f32_16x16x32_bf16(a1[t], b1[u], acc[t][u], 0, 0, 0);
    }

    // epilogue: bf16 blocked store + per-wave colmax partial (no atomics)
    int nQB = S >> 7;
    size_t base = ((size_t)(blockIdx.y * nQB + blockIdx.x)) * 16384
                + (size_t)(wave * 4096 + quad * 64 + lm * 4);
    float cmax[4] = {-INFINITY, -INFINITY, -INFINITY, -INFINITY};
#pragma unroll
    for (int t = 0; t < 4; t++)
#pragma unroll
        for (int u = 0; u < 4; u++) {
            f32x4 v = acc[t][u];
            ushort4_t o;
            o.x = f2bf(v.x); o.y = f2bf(v.y); o.z = f2bf(v.z); o.w = f2bf(v.w);
            *(ushort4_t*)(sim + base + (t * 4 + u) * 256) = o;
            float mx = fmaxf(fmaxf(bf2f(o.x), bf2f(o.y)), fmaxf(bf2f(o.z), bf2f(o.w)));
            cmax[u] = fmaxf(cmax[u], mx);
        }
    // r = by*2 + (wave&1); q = q0 + wn + u*16 + lm  (lanes<16 write, 64 consecutive)
    int r = blockIdx.y * 2 + (wave & 1);
#pragma unroll
    for (int u = 0; u < 4; u++) {
        float m = cmax[u];
        m = fmaxf(m, __shfl_xor(m, 16, 64));
        m = fmaxf(m, __shfl_xor(m, 32, 64));
        if (lane < 16) cmPart[(size_t)r * S + q0 + wn + u * 16 + lane] = m;
    }
}

// ---- reduce colmax partials -> coef {c0, c1} per q ----
__global__ __launch_bounds__(256) void colmax_reduce(
    const float* __restrict__ cmPart, float2* __restrict__ coef,
    int S, int R, size_t cmStride) {
    int z = blockIdx.y;
    cmPart += (size_t)z * cmStride; coef += (size_t)z * S;
    int q = blockIdx.x * 256 + threadIdx.x;
    float m = cmPart[q];
    for (int r = 1; r < R; r++) m = fmaxf(m, cmPart[(size_t)r * S + q]);
    float c1 = 1.f / ((1.f - m) * 0.5f + MRF_EPS);
    coef[q] = make_float2(2.f - c1, c1);
}

// ---- column sums of dist ----
__global__ __launch_bounds__(256) void colsum_kernel(
    const ushort_t* __restrict__ sim, const float2* __restrict__ coef,
    float* __restrict__ colsum, int S, size_t simStride) {
    int z = blockIdx.z;
    sim += (size_t)z * simStride; coef += (size_t)z * S; colsum += (size_t)z * S;
    int tid = threadIdx.x, lane = tid & 63;
    int u = lane >> 4, lm = lane & 15;
    int sub = (tid >> 6) & 1, cg = tid >> 7;
    int bx = blockIdx.x, by = blockIdx.y;
    int nQB = S >> 7;
    int q = bx * 128 + cg * 64 + u * 16 + lm;
    float2 cc = coef[q];
    float c0 = cc.x, c1 = cc.y;
    const ushort_t* base = sim + ((size_t)(by * nQB + bx)) * 16384
                         + (size_t)((sub | (cg << 1)) * 4096 + u * 256 + lm * 4);
    float s = 0.f;
#pragma unroll
    for (int t = 0; t < 4; t++)
#pragma unroll
        for (int quad = 0; quad < 4; quad++) {
            ushort4_t w = *(const ushort4_t*)(base + t * 1024 + quad * 64);
            s += __expf(c0 + c1 * bf2f(w.x)) + __expf(c0 + c1 * bf2f(w.y))
               + __expf(c0 + c1 * bf2f(w.z)) + __expf(c0 + c1 * bf2f(w.w));
        }
    atomicAdd(colsum + q, s);
}

// ---- fold colsum into coef: c0' = c0 - ln(colsum) ----
__global__ __launch_bounds__(256) void coef_fold(
    float2* __restrict__ coef, const float* __restrict__ colsum, int S) {
    int z = blockIdx.y;
    coef += (size_t)z * S; colsum += (size_t)z * S;
    int q = blockIdx.x * 256 + threadIdx.x;
    coef[q].x -= logf(colsum[q]);
}

// ---- row max of cs = exp(c0' + c1*v), fused partial sum ----
__global__ __launch_bounds__(256) void rowmax_kernel(
    const ushort_t* __restrict__ sim, const float2* __restrict__ coef,
    float* __restrict__ acc, int S, size_t simStride) {
    int z = blockIdx.y;
    sim += (size_t)z * simStride; coef += (size_t)z * S;
    int wave = threadIdx.x >> 6, lane = threadIdx.x & 63;
    int g = blockIdx.x * 4 + wave;
    int by = g >> 5, rem = g & 31;
    int sub = rem >> 4, t = (rem >> 2) & 3, quad = rem & 3;
    int u = lane >> 4, lm = lane & 15;
    int nQB = S >> 7;
    f32x4 m = {-INFINITY, -INFINITY, -INFINITY, -INFINITY};
    for (int bx = 0; bx < nQB; bx++) {
#pragma unroll
        for (int cg = 0; cg < 2; cg++) {
            int q = bx * 128 + cg * 64 + u * 16 + lm;
            float2 cc = coef[q];
            const ushort_t* ptr = sim + ((size_t)(by * nQB + bx)) * 16384
                                + (size_t)((sub | (cg << 1)) * 4096 + (t * 4 + u) * 256 + quad * 64 + lm * 4);
            ushort4_t w = *(const ushort4_t*)ptr;
            m[0] = fmaxf(m[0], cc.x + cc.y * bf2f(w.x));
            m[1] = fmaxf(m[1], cc.x + cc.y * bf2f(w.y));
            m[2] = fmaxf(m[2], cc.x + cc.y * bf2f(w.z));
            m[3] = fmaxf(m[3], cc.x + cc.y * bf2f(w.w));
        }
    }
    // NOTE: max of exponent args per q-chunk is NOT the max of exp across q,
    // because c0/c1 vary with q — so we must exp before maxing. Do exp at
    // the last moment: we kept args only within a fixed q (same coef) — but q
    // varies across lanes/iters, so exp must be inside. Correct version below.
    (void)m;
    f32x4 mm = {-INFINITY, -INFINITY, -INFINITY, -INFINITY};
    for (int bx = 0; bx < nQB; bx++) {
#pragma unroll
        for (int cg = 0; cg < 2; cg++) {
            int q = bx * 128 + cg * 64 + u * 16 + lm;
            float2 cc = coef[q];
            const ushort_t* ptr = sim + ((size_t)(by * nQB + bx)) * 16384
                                + (size_t)((sub | (cg << 1)) * 4096 + (t * 4 + u) * 256 + quad * 64 + lm * 4);
            ushort4_t w = *(const ushort4_t*)ptr;
            mm[0] = fmaxf(mm[0], __expf(cc.x + cc.y * bf2f(w.x)));
            mm[1] = fmaxf(mm[1], __expf(cc.x + cc.y * bf2f(w.y)));
            mm[2] = fmaxf(mm[2], __expf(cc.x + cc.y * bf2f(w.z)));
            mm[3] = fmaxf(mm[3], __expf(cc.x + cc.y * bf2f(w.w)));
        }
    }
#pragma unroll
    for (int off = 32; off >= 1; off >>= 1)
#pragma unroll
        for (int e = 0; e < 4; e++)
            mm[e] = fmaxf(mm[e], __shfl_xor(mm[e], off, 64));
    __shared__ float partial[4];
    if (lane == 0) partial[wave] = mm[0] + mm[1] + mm[2] + mm[3];
    __syncthreads();
    if (threadIdx.x == 0)
        atomicAdd(acc + z, partial[0] + partial[1] + partial[2] + partial[3]);
}

__global__ void finalize_kernel(const float* __restrict__ acc, float* __restrict__ out) {
    float loss = 0.f;
    for (int b = 0; b < 4; b++) loss += -logf(acc[b] * (1.f / 4096.f));
    for (int b = 0; b < 4; b++) loss += -2.f * logf(acc[4 + b] * (1.f / 1024.f));
    out[0] = loss;
}

extern "C" void kernel_launch(void* const* d_in, const int* in_sizes, int n_in,
                              void* d_out, int out_size, void* d_ws, size_t ws_size,
                              hipStream_t stream) {
    const float* gen3 = (const float*)d_in[0];
    const float* tar3 = (const float*)d_in[1];
    const float* gen4 = (const float*)d_in[2];
    const float* tar4 = (const float*)d_in[3];

    char* wsb = (char*)d_ws;
    ushort_t* sim = (ushort_t*)wsb;                          // 33,554,432 ushort (67.1 MB)
    ushort_t* gnT = (ushort_t*)(wsb + 67108864);             // 2,097,152 ushort
    ushort_t* tnT = (ushort_t*)(wsb + 71303168);             // 2,097,152 ushort
    float* cmPart = (float*)(wsb + 75497472);                // 524,288 floats
    float2* coef = (float2*)(wsb + 77594624);                // 8,192 float2
    float* colsum = (float*)(wsb + 77660160);                // 8,192 floats
    float* mean = (float*)(wsb + 77692928);                  // 16,384
    float* rg = mean + 16384;
    float* rt = rg + 16384;
    float* acc = rt + 16384;                                 // 8
    // total ~77.9 MB (< 84.1 MB proven available in R2)

    zero_acc<<<1, 64, 0, stream>>>(acc);

    // ---- layer 0: C=256, S=4096, 2 rounds x 2 batches ----
    {
        const int C = 256, S = 4096, R = 2 * (S / 128);
        stats_kernel<<<dim3(S / 16, 4), 256, 0, stream>>>(gen3, tar3, mean, rg, rt, C, S);
        for (int r = 0; r < 2; r++) {
            apply_kernel<<<dim3(S / 64, C / 64, 2), 256, 0, stream>>>(
                gen3, tar3, mean, rg, rt, gnT, tnT, C, S, 2 * r);
            init_colsum<<<(2 * S + 255) / 256, 256, 0, stream>>>(colsum, 2 * S);
            gemm_mfma<256><<<dim3(S / 128, S / 128, 2), 256, 0, stream>>>(
                tnT, gnT, sim, cmPart, S, (size_t)S * C, (size_t)S * S, (size_t)R * S);
            colmax_reduce<<<dim3(S / 256, 2), 256, 0, stream>>>(
                cmPart, coef, S, R, (size_t)R * S);
            colsum_kernel<<<dim3(S / 128, S / 128, 2), 256, 0, stream>>>(
                sim, coef, colsum, S, (size_t)S * S);
            coef_fold<<<dim3(S / 256, 2), 256, 0, stream>>>(coef, colsum, S);
            rowmax_kernel<<<dim3(S / 16, 2), 256, 0, stream>>>(
                sim, coef, acc + 2 * r, S, (size_t)S * S);
        }
    }
    // ---- layer 1: C=512, S=1024, z=4 ----
    {
        const int C = 512, S = 1024, R = 2 * (S / 128);
        stats_kernel<<<dim3(S / 16, 4), 256, 0, stream>>>(gen4, tar4, mean, rg, rt, C, S);
        apply_kernel<<<dim3(S / 64, C / 64, 4), 256, 0, stream>>>(
            gen4, tar4, mean, rg, rt, gnT, tnT, C, S, 0);
        init_colsum<<<(4 * S + 255) / 256, 256, 0, stream>>>(colsum, 4 * S);
        gemm_mfma<512><<<dim3(S / 128, S / 128, 4), 256, 0, stream>>>(
            tnT, gnT, sim, cmPart, S, (size_t)S * C, (size_t)S * S, (size_t)R * S);
        colmax_reduce<<<dim3(S / 256, 4), 256, 0, stream>>>(
            cmPart, coef, S, R, (size_t)R * S);
        colsum_kernel<<<dim3(S / 128, S / 128, 4), 256, 0, stream>>>(
            sim, coef, colsum, S, (size_t)S * S);
        coef_fold<<<dim3(S / 256, 4), 256, 0, stream>>>(coef, colsum, S);
        rowmax_kernel<<<dim3(S / 16, 4), 256, 0, stream>>>(
            sim, coef, acc + 4, S, (size_t)S * S);
    }
    finalize_kernel<<<1, 1, 0, stream>>>(acc, (float*)d_out);
}

// Round 7
// 274.873 us; speedup vs baseline: 6.5400x; 1.1447x over previous
//
#include <hip/hip_runtime.h>
#include <math.h>

// IDMRFLoss on MI355X — R7: single-round z=4 layer3 (ws is ~256MB per the
// harness poison fill), log2-domain coefs, rowmax = affine max + 1 exp2/row,
// launch count 24 -> 16.
//
// Layer 0 (relu3_2): B=4, C=256, S=4096, weight 1.0
// Layer 1 (relu4_2): B=4, C=512, S=1024, weight 2.0 (style + content)
//
// Swizzled operand layout (per batch-slot, matrix [S][K] bf16):
//   elem(row,k) at ((row>>4)*(K/8) + (k>>3))*128 + (row&15)*8 + (k&7)
// sim blocked bf16 layout (per 128x128 block at (by,bx)):
//   elem = (by*nQB+bx)*16384 + wave*4096 + (t*4+u)*256 + quad*64 + lm*4 + r
//   p = by*128 + (wave&1)*64 + t*16 + quad*4 + r ; q = bx*128 + (wave>>1)*64 + u*16 + lm
//
// Math (per z): c1 = 1/((1-colmax)/2+eps); log2-domain: c1L=c1*log2e,
// c0L=(2-c1)*log2e. colsum_q = sum_p 2^(c0L+c1L*v). After fold
// c0L' = c0L - log2(colsum): kmax_p = 2^(max_q (c0L' + c1L*v)).

#define MRF_EPS 1e-5f
#define LOG2E 1.44269504088896340736f

typedef __attribute__((ext_vector_type(8))) short bf16x8;
typedef __attribute__((ext_vector_type(4))) float f32x4;
typedef unsigned short ushort_t;
struct __align__(8) ushort4_t { ushort_t x, y, z, w; };
struct __align__(16) ushort8_t { ushort_t v[8]; };

__device__ __forceinline__ ushort_t f2bf(float x) {
    unsigned u = __float_as_uint(x);
    u += 0x7FFFu + ((u >> 16) & 1u);
    return (ushort_t)(u >> 16);
}
__device__ __forceinline__ float bf2f(ushort_t u) {
    return __uint_as_float(((unsigned)u) << 16);
}

// ---- stats: per position mean(tar), 1/||g-m||, 1/||t-m|| (single pass) ----
__global__ __launch_bounds__(256) void stats_kernel(
    const float* __restrict__ gen, const float* __restrict__ tar,
    float* __restrict__ mean, float* __restrict__ rg, float* __restrict__ rt,
    int C, int S) {
    int tid = threadIdx.x, pq = tid & 3, cs = tid >> 2;
    int b = blockIdx.y;
    int s0 = blockIdx.x * 16 + pq * 4;
    const float* g = gen + (size_t)b * C * S + s0;
    const float* t = tar + (size_t)b * C * S + s0;

    f32x4 st = {0.f, 0.f, 0.f, 0.f}, st2 = st, sg = st, sg2 = st;
    for (int c = cs; c < C; c += 64) {
        f32x4 tv = *(const f32x4*)(t + (size_t)c * S);
        f32x4 gv = *(const f32x4*)(g + (size_t)c * S);
        st += tv; st2 += tv * tv; sg += gv; sg2 += gv * gv;
    }
    __shared__ f32x4 red[4][4][64];
    __shared__ f32x4 red2[4][4][4];
    red[0][pq][cs] = st; red[1][pq][cs] = st2; red[2][pq][cs] = sg; red[3][pq][cs] = sg2;
    __syncthreads();
    if (tid < 64) {
        int s_ = tid >> 4, p_ = (tid >> 2) & 3, part = tid & 3;
        f32x4 s = red[s_][p_][part * 16];
#pragma unroll
        for (int j = 1; j < 16; j++) s += red[s_][p_][part * 16 + j];
        red2[s_][p_][part] = s;
    }
    __syncthreads();
    if (tid < 4) {
        f32x4 sts = red2[0][tid][0] + red2[0][tid][1] + red2[0][tid][2] + red2[0][tid][3];
        f32x4 st2s = red2[1][tid][0] + red2[1][tid][1] + red2[1][tid][2] + red2[1][tid][3];
        f32x4 sgs = red2[2][tid][0] + red2[2][tid][1] + red2[2][tid][2] + red2[2][tid][3];
        f32x4 sg2s = red2[3][tid][0] + red2[3][tid][1] + red2[3][tid][2] + red2[3][tid][3];
        f32x4 m, vrt, vrg;
        float invC = 1.f / (float)C;
#pragma unroll
        for (int e = 0; e < 4; e++) {
            float mm = sts[e] * invC;
            m[e] = mm;
            vrt[e] = rsqrtf(st2s[e] - mm * sts[e]);
            vrg[e] = rsqrtf(sg2s[e] - 2.f * mm * sgs[e] + mm * sts[e]);
        }
        int idx = b * S + blockIdx.x * 16 + tid * 4;
        *(f32x4*)(mean + idx) = m;
        *(f32x4*)(rt + idx) = vrt;
        *(f32x4*)(rg + idx) = vrg;
    }
}

// ---- apply: normalize + transpose -> swizzled MFMA layout bf16 (slot z) ----
__global__ __launch_bounds__(256) void apply_kernel(
    const float* __restrict__ gen, const float* __restrict__ tar,
    const float* __restrict__ mean, const float* __restrict__ rg, const float* __restrict__ rt,
    ushort_t* __restrict__ gnT, ushort_t* __restrict__ tnT, int C, int S, int batchBase) {
    int tid = threadIdx.x;
    int slot = blockIdx.z, b = batchBase + slot;
    int s0 = blockIdx.x * 64, c0 = blockIdx.y * 64;
    const float* g = gen + (size_t)b * C * S;
    const float* t = tar + (size_t)b * C * S;
    int tx = tid & 63, tw = tid >> 6;
    int sidx = b * S + s0 + tx;
    float m = mean[sidx], rgv = rg[sidx], rtv = rt[sidx];

    __shared__ ushort_t tg[64][72], tt_[64][72];
#pragma unroll
    for (int i = 0; i < 16; i++) {
        int cl = tw * 16 + i;
        float gv = g[(size_t)(c0 + cl) * S + s0 + tx];
        float tv = t[(size_t)(c0 + cl) * S + s0 + tx];
        tg[tx][cl] = f2bf((gv - m) * rgv);
        tt_[tx][cl] = f2bf((tv - m) * rtv);
    }
    __syncthreads();
    int KC = C >> 3;
#pragma unroll
    for (int j = 0; j < 2; j++) {
        int p = j * 256 + tid;
        int s = p & 63, ch = p >> 6;
        int row = s0 + s;
        int r16 = row >> 4, lm = row & 15;
        size_t off = (size_t)slot * S * C + (((size_t)r16 * KC + (c0 >> 3) + ch) * 16 + lm) * 8;
        *(ushort8_t*)(gnT + off) = *(const ushort8_t*)&tg[s][ch * 8];
        *(ushort8_t*)(tnT + off) = *(const ushort8_t*)&tt_[s][ch * 8];
    }
}

__global__ void zero_acc(float* __restrict__ acc) {
    if (threadIdx.x < 8) acc[threadIdx.x] = 0.f;
}

// ---- MFMA GEMM, LDS-free, no atomics: sim + colmax partials ----
template <int K>
__global__ __launch_bounds__(256) void gemm_mfma(
    const ushort_t* __restrict__ A, const ushort_t* __restrict__ B,
    ushort_t* __restrict__ sim, float* __restrict__ cmPart,
    int S, size_t abStride, size_t simStride, size_t cmStride) {
    int z = blockIdx.z;
    A += (size_t)z * abStride; B += (size_t)z * abStride;
    sim += (size_t)z * simStride; cmPart += (size_t)z * cmStride;

    const int tid = threadIdx.x;
    const int lane = tid & 63, wave = tid >> 6;
    const int wm = (wave & 1) * 64, wn = (wave >> 1) * 64;
    const int lm = lane & 15, quad = lane >> 4;
    const int p0 = blockIdx.y * 128, q0 = blockIdx.x * 128;

    constexpr int KC = K / 8;
    constexpr int KS = K / 32;

    const ushort_t* Ab = A + ((size_t)((p0 + wm) >> 4) * KC + quad) * 128 + lm * 8;
    const ushort_t* Bb = B + ((size_t)((q0 + wn) >> 4) * KC + quad) * 128 + lm * 8;

    f32x4 acc[4][4];
#pragma unroll
    for (int t = 0; t < 4; t++)
#pragma unroll
        for (int u = 0; u < 4; u++) acc[t][u] = (f32x4){0.f, 0.f, 0.f, 0.f};

    bf16x8 a0[4], b0[4], a1[4], b1[4];
#pragma unroll
    for (int t = 0; t < 4; t++) {
        a0[t] = *(const bf16x8*)(Ab + (size_t)(t * KC) * 128);
        b0[t] = *(const bf16x8*)(Bb + (size_t)(t * KC) * 128);
    }
#pragma unroll
    for (int ks = 0; ks < KS; ks += 2) {
#pragma unroll
        for (int t = 0; t < 4; t++) {
            a1[t] = *(const bf16x8*)(Ab + (size_t)(t * KC + (ks + 1) * 4) * 128);
            b1[t] = *(const bf16x8*)(Bb + (size_t)(t * KC + (ks + 1) * 4) * 128);
        }
#pragma unroll
        for (int t = 0; t < 4; t++)
#pragma unroll
            for (int u = 0; u < 4; u++)
                acc[t][u] = __builtin_amdgcn_mfma_f32_16x16x32_bf16(a0[t], b0[u], acc[t][u], 0, 0, 0);
        if (ks + 2 < KS) {
#pragma unroll
            for (int t = 0; t < 4; t++) {
                a0[t] = *(const bf16x8*)(Ab + (size_t)(t * KC + (ks + 2) * 4) * 128);
                b0[t] = *(const bf16x8*)(Bb + (size_t)(t * KC + (ks + 2) * 4) * 128);
            }
        }
#pragma unroll
        for (int t = 0; t < 4; t++)
#pragma unroll
            for (int u = 0; u < 4; u++)
                acc[t][u] = __builtin_amdgcn_mfma_f32_16x16x32_bf16(a1[t], b1[u], acc[t][u], 0, 0, 0);
    }

    int nQB = S >> 7;
    size_t base = ((size_t)(blockIdx.y * nQB + blockIdx.x)) * 16384
                + (size_t)(wave * 4096 + quad * 64 + lm * 4);
    float cmax[4] = {-INFINITY, -INFINITY, -INFINITY, -INFINITY};
#pragma unroll
    for (int t = 0; t < 4; t++)
#pragma unroll
        for (int u = 0; u < 4; u++) {
            f32x4 v = acc[t][u];
            ushort4_t o;
            o.x = f2bf(v.x); o.y = f2bf(v.y); o.z = f2bf(v.z); o.w = f2bf(v.w);
            *(ushort4_t*)(sim + base + (t * 4 + u) * 256) = o;
            float mx = fmaxf(fmaxf(bf2f(o.x), bf2f(o.y)), fmaxf(bf2f(o.z), bf2f(o.w)));
            cmax[u] = fmaxf(cmax[u], mx);
        }
    int r = blockIdx.y * 2 + (wave & 1);
#pragma unroll
    for (int u = 0; u < 4; u++) {
        float m = cmax[u];
        m = fmaxf(m, __shfl_xor(m, 16, 64));
        m = fmaxf(m, __shfl_xor(m, 32, 64));
        if (lane < 16) cmPart[(size_t)r * S + q0 + wn + u * 16 + lane] = m;
    }
}

// ---- reduce colmax partials -> log2-scaled coef {c0L, c1L}; zero colsum ----
__global__ __launch_bounds__(256) void colmax_reduce(
    const float* __restrict__ cmPart, float2* __restrict__ coef,
    float* __restrict__ colsum, int S, int R, size_t cmStride) {
    int z = blockIdx.y;
    cmPart += (size_t)z * cmStride; coef += (size_t)z * S; colsum += (size_t)z * S;
    int q = blockIdx.x * 256 + threadIdx.x;
    float m = cmPart[q];
    for (int r = 1; r < R; r++) m = fmaxf(m, cmPart[(size_t)r * S + q]);
    float c1 = 1.f / ((1.f - m) * 0.5f + MRF_EPS);
    coef[q] = make_float2((2.f - c1) * LOG2E, c1 * LOG2E);
    colsum[q] = 0.f;
}

// ---- column sums of dist (2^x domain) ----
__global__ __launch_bounds__(256) void colsum_kernel(
    const ushort_t* __restrict__ sim, const float2* __restrict__ coef,
    float* __restrict__ colsum, int S, size_t simStride) {
    int z = blockIdx.z;
    sim += (size_t)z * simStride; coef += (size_t)z * S; colsum += (size_t)z * S;
    int tid = threadIdx.x, lane = tid & 63;
    int u = lane >> 4, lm = lane & 15;
    int sub = (tid >> 6) & 1, cg = tid >> 7;
    int bx = blockIdx.x, by = blockIdx.y;
    int nQB = S >> 7;
    int q = bx * 128 + cg * 64 + u * 16 + lm;
    float2 cc = coef[q];
    float c0 = cc.x, c1 = cc.y;
    const ushort_t* base = sim + ((size_t)(by * nQB + bx)) * 16384
                         + (size_t)((sub | (cg << 1)) * 4096 + u * 256 + lm * 4);
    float s = 0.f;
#pragma unroll
    for (int t = 0; t < 4; t++)
#pragma unroll
        for (int quad = 0; quad < 4; quad++) {
            ushort4_t w = *(const ushort4_t*)(base + t * 1024 + quad * 64);
            s += exp2f(c0 + c1 * bf2f(w.x)) + exp2f(c0 + c1 * bf2f(w.y))
               + exp2f(c0 + c1 * bf2f(w.z)) + exp2f(c0 + c1 * bf2f(w.w));
        }
    atomicAdd(colsum + q, s);
}

// ---- fold colsum into coef: c0L' = c0L - log2(colsum) ----
__global__ __launch_bounds__(256) void coef_fold(
    float2* __restrict__ coef, const float* __restrict__ colsum, int S) {
    int z = blockIdx.y;
    coef += (size_t)z * S; colsum += (size_t)z * S;
    int q = blockIdx.x * 256 + threadIdx.x;
    coef[q].x -= log2f(colsum[q]);
}

// ---- row max of affine args (exp2 once per row), fused partial sum ----
__global__ __launch_bounds__(256) void rowmax_kernel(
    const ushort_t* __restrict__ sim, const float2* __restrict__ coef,
    float* __restrict__ acc, int S, size_t simStride) {
    int z = blockIdx.y;
    sim += (size_t)z * simStride; coef += (size_t)z * S;
    int wave = threadIdx.x >> 6, lane = threadIdx.x & 63;
    int g = blockIdx.x * 4 + wave;
    int by = g >> 5, rem = g & 31;
    int sub = rem >> 4, t = (rem >> 2) & 3, quad = rem & 3;
    int u = lane >> 4, lm = lane & 15;
    int nQB = S >> 7;
    // max_q 2^(c0'+c1*v) = 2^(max_q (c0'+c1*v)) — exp2 is monotone.
    f32x4 m = {-INFINITY, -INFINITY, -INFINITY, -INFINITY};
    for (int bx = 0; bx < nQB; bx++) {
#pragma unroll
        for (int cg = 0; cg < 2; cg++) {
            int q = bx * 128 + cg * 64 + u * 16 + lm;
            float2 cc = coef[q];
            const ushort_t* ptr = sim + ((size_t)(by * nQB + bx)) * 16384
                                + (size_t)((sub | (cg << 1)) * 4096 + (t * 4 + u) * 256 + quad * 64 + lm * 4);
            ushort4_t w = *(const ushort4_t*)ptr;
            m[0] = fmaxf(m[0], cc.x + cc.y * bf2f(w.x));
            m[1] = fmaxf(m[1], cc.x + cc.y * bf2f(w.y));
            m[2] = fmaxf(m[2], cc.x + cc.y * bf2f(w.z));
            m[3] = fmaxf(m[3], cc.x + cc.y * bf2f(w.w));
        }
    }
#pragma unroll
    for (int off = 32; off >= 1; off >>= 1)
#pragma unroll
        for (int e = 0; e < 4; e++)
            m[e] = fmaxf(m[e], __shfl_xor(m[e], off, 64));
    __shared__ float partial[4];
    if (lane == 0)
        partial[wave] = exp2f(m[0]) + exp2f(m[1]) + exp2f(m[2]) + exp2f(m[3]);
    __syncthreads();
    if (threadIdx.x == 0)
        atomicAdd(acc + z, partial[0] + partial[1] + partial[2] + partial[3]);
}

__global__ void finalize_kernel(const float* __restrict__ acc, float* __restrict__ out) {
    float loss = 0.f;
    for (int b = 0; b < 4; b++) loss += -logf(acc[b] * (1.f / 4096.f));
    for (int b = 0; b < 4; b++) loss += -2.f * logf(acc[4 + b] * (1.f / 1024.f));
    out[0] = loss;
}

extern "C" void kernel_launch(void* const* d_in, const int* in_sizes, int n_in,
                              void* d_out, int out_size, void* d_ws, size_t ws_size,
                              hipStream_t stream) {
    const float* gen3 = (const float*)d_in[0];
    const float* tar3 = (const float*)d_in[1];
    const float* gen4 = (const float*)d_in[2];
    const float* tar4 = (const float*)d_in[3];

    // zB3 = layer3 batches per round (deterministic in ws_size -> capture-safe)
    const int zB3 = (ws_size >= (size_t)170 * 1024 * 1024) ? 4 : 2;

    char* wsb = (char*)d_ws;
    size_t off = 0;
    auto alloc = [&](size_t bytes) {
        void* p = wsb + off;
        off += (bytes + 255) & ~(size_t)255;
        return p;
    };
    ushort_t* sim = (ushort_t*)alloc((size_t)zB3 * 4096 * 4096 * 2);
    ushort_t* gnT = (ushort_t*)alloc((size_t)zB3 * 4096 * 256 * 2);
    ushort_t* tnT = (ushort_t*)alloc((size_t)zB3 * 4096 * 256 * 2);
    float* cmPart = (float*)alloc((size_t)zB3 * 64 * 4096 * 4);
    float2* coef = (float2*)alloc(4 * 4096 * sizeof(float2));
    float* colsum = (float*)alloc(4 * 4096 * 4);
    float* mean = (float*)alloc(4 * 4096 * 4);
    float* rg = (float*)alloc(4 * 4096 * 4);
    float* rt = (float*)alloc(4 * 4096 * 4);
    float* acc = (float*)alloc(64 * 4);

    zero_acc<<<1, 64, 0, stream>>>(acc);

    // ---- layer 0: C=256, S=4096 ----
    {
        const int C = 256, S = 4096, R = 2 * (S / 128);
        stats_kernel<<<dim3(S / 16, 4), 256, 0, stream>>>(gen3, tar3, mean, rg, rt, C, S);
        for (int r0 = 0; r0 < 4; r0 += zB3) {
            apply_kernel<<<dim3(S / 64, C / 64, zB3), 256, 0, stream>>>(
                gen3, tar3, mean, rg, rt, gnT, tnT, C, S, r0);
            gemm_mfma<256><<<dim3(S / 128, S / 128, zB3), 256, 0, stream>>>(
                tnT, gnT, sim, cmPart, S, (size_t)S * C, (size_t)S * S, (size_t)R * S);
            colmax_reduce<<<dim3(S / 256, zB3), 256, 0, stream>>>(
                cmPart, coef, colsum, S, R, (size_t)R * S);
            colsum_kernel<<<dim3(S / 128, S / 128, zB3), 256, 0, stream>>>(
                sim, coef, colsum, S, (size_t)S * S);
            coef_fold<<<dim3(S / 256, zB3), 256, 0, stream>>>(coef, colsum, S);
            rowmax_kernel<<<dim3(S / 16, zB3), 256, 0, stream>>>(
                sim, coef, acc + r0, S, (size_t)S * S);
        }
    }
    // ---- layer 1: C=512, S=1024, z=4 ----
    {
        const int C = 512, S = 1024, R = 2 * (S / 128);
        stats_kernel<<<dim3(S / 16, 4), 256, 0, stream>>>(gen4, tar4, mean, rg, rt, C, S);
        apply_kernel<<<dim3(S / 64, C / 64, 4), 256, 0, stream>>>(
            gen4, tar4, mean, rg, rt, gnT, tnT, C, S, 0);
        gemm_mfma<512><<<dim3(S / 128, S / 128, 4), 256, 0, stream>>>(
            tnT, gnT, sim, cmPart, S, (size_t)S * C, (size_t)S * S, (size_t)R * S);
        colmax_reduce<<<dim3(S / 256, 4), 256, 0, stream>>>(
            cmPart, coef, colsum, S, R, (size_t)R * S);
        colsum_kernel<<<dim3(S / 128, S / 128, 4), 256, 0, stream>>>(
            sim, coef, colsum, S, (size_t)S * S);
        coef_fold<<<dim3(S / 256, 4), 256, 0, stream>>>(coef, colsum, S);
        rowmax_kernel<<<dim3(S / 16, 4), 256, 0, stream>>>(
            sim, coef, acc + 4, S, (size_t)S * S);
    }
    finalize_kernel<<<1, 1, 0, stream>>>(acc, (float*)d_out);
}